// Round 2
// baseline (1629.267 us; speedup 1.0000x reference)
//
#include <hip/hip_runtime.h>

typedef __bf16 bf16x8 __attribute__((ext_vector_type(8)));
typedef float f32x4 __attribute__((ext_vector_type(4)));
typedef unsigned short u16x8 __attribute__((ext_vector_type(8)));

#define B_SZ 2
#define T_SEQ 2048
#define D_MODEL 2048
#define N_HEADS 16
#define D_HEAD 128
#define D_FF 8192
#define BT (B_SZ * T_SEQ)
#define MLP_CHUNK 2048

__device__ __forceinline__ unsigned short f2bf(float f) {
  unsigned int u = __builtin_bit_cast(unsigned int, f);
  u += 0x7FFFu + ((u >> 16) & 1u);
  return (unsigned short)(u >> 16);
}
__device__ __forceinline__ float bf2f(unsigned short h) {
  unsigned int u = ((unsigned int)h) << 16;
  return __builtin_bit_cast(float, u);
}

__device__ __forceinline__ void load_lds16(const void* g, void* l) {
  __builtin_amdgcn_global_load_lds(
      (const __attribute__((address_space(1))) unsigned int*)g,
      (__attribute__((address_space(3))) unsigned int*)l, 16, 0, 0);
}

// ---------------- transpose + cast: in fp32 [R][C] -> out bf16 [C][R] -------
__global__ __launch_bounds__(256) void transpose_cast_kernel(
    const float* __restrict__ in, unsigned short* __restrict__ out, int R, int C) {
  __shared__ float tile[32][33];
  const int tx = threadIdx.x, ty = threadIdx.y;
  const int c0 = blockIdx.x * 32, r0 = blockIdx.y * 32;
#pragma unroll
  for (int i = 0; i < 4; ++i)
    tile[ty + 8 * i][tx] = in[(long)(r0 + ty + 8 * i) * C + c0 + tx];
  __syncthreads();
#pragma unroll
  for (int i = 0; i < 4; ++i)
    out[(long)(c0 + ty + 8 * i) * R + r0 + tx] = f2bf(tile[tx][ty + 8 * i]);
}

// ---------------- RMSNorm fp32 row -> bf16 ----------------------------------
__global__ __launch_bounds__(256) void rmsnorm_cast_kernel(
    const float* __restrict__ x, const float* __restrict__ gw,
    unsigned short* __restrict__ out) {
  const int row = blockIdx.x;
  const int tid = threadIdx.x;
  const float* xr = x + (long)row * D_MODEL;
  float4 a = *(const float4*)(xr + tid * 8);
  float4 b = *(const float4*)(xr + tid * 8 + 4);
  float ss = a.x * a.x + a.y * a.y + a.z * a.z + a.w * a.w +
             b.x * b.x + b.y * b.y + b.z * b.z + b.w * b.w;
#pragma unroll
  for (int d = 1; d < 64; d <<= 1) ss += __shfl_xor(ss, d);
  __shared__ float part[4];
  if ((tid & 63) == 0) part[tid >> 6] = ss;
  __syncthreads();
  ss = part[0] + part[1] + part[2] + part[3];
  const float rs = rsqrtf(ss * (1.0f / D_MODEL) + 1e-6f);
  float4 g0 = *(const float4*)(gw + tid * 8);
  float4 g1 = *(const float4*)(gw + tid * 8 + 4);
  ushort4 o0, o1;
  o0.x = f2bf(a.x * rs * g0.x); o0.y = f2bf(a.y * rs * g0.y);
  o0.z = f2bf(a.z * rs * g0.z); o0.w = f2bf(a.w * rs * g0.w);
  o1.x = f2bf(b.x * rs * g1.x); o1.y = f2bf(b.y * rs * g1.y);
  o1.z = f2bf(b.z * rs * g1.z); o1.w = f2bf(b.w * rs * g1.w);
  unsigned short* op = out + (long)row * D_MODEL + tid * 8;
  *(ushort4*)op = o0;
  *(ushort4*)(op + 4) = o1;
}

// ---------------- GEMM: C[M,N] = A[M,K](bf16) @ Bt[N,K](bf16)^T -------------
// m97-style: 128x128 tile, BK=32, 4 waves, global_load_lds staging.
template <bool OUT_BF16, bool ADD_RES>
__global__ __launch_bounds__(256) void gemm_bt_kernel(
    const unsigned short* __restrict__ A, const unsigned short* __restrict__ Bt,
    void* __restrict__ Cout, const float* __restrict__ resid,
    int M, int N, int K) {
  __shared__ unsigned short As[128 * 32];
  __shared__ unsigned short Bs[128 * 32];
  const int tid = threadIdx.x;
  const int w = tid >> 6, lane = tid & 63, g = lane >> 4, c = lane & 15;
  const int m0 = blockIdx.y * 128, n0 = blockIdx.x * 128;
  const int wm = (w >> 1) * 64, wn = (w & 1) * 64;
  const int srow = lane >> 2;        // 16 rows per 1KB chunk
  const int scol = (lane & 3) * 8;   // 4 lanes x 8 bf16 per row
  const int ch0 = w * 2;
  f32x4 acc[4][4] = {};
  const int nkt = K >> 5;
  const unsigned short* Abase = A + (long)m0 * K + scol;
  const unsigned short* Bbase = Bt + (long)n0 * K + scol;
  for (int kt = 0; kt < nkt; ++kt) {
    __syncthreads();
#pragma unroll
    for (int i = 0; i < 2; ++i) {
      const int ch = ch0 + i;
      load_lds16(Abase + (long)(ch * 16 + srow) * K + kt * 32, &As[ch * 512]);
      load_lds16(Bbase + (long)(ch * 16 + srow) * K + kt * 32, &Bs[ch * 512]);
    }
    __syncthreads();
    bf16x8 fa[4], fb[4];
#pragma unroll
    for (int m = 0; m < 4; ++m)
      fa[m] = *(const bf16x8*)(As + (wm + m * 16 + c) * 32 + g * 8);
#pragma unroll
    for (int n = 0; n < 4; ++n)
      fb[n] = *(const bf16x8*)(Bs + (wn + n * 16 + c) * 32 + g * 8);
#pragma unroll
    for (int m = 0; m < 4; ++m)
#pragma unroll
      for (int n = 0; n < 4; ++n)
        acc[m][n] = __builtin_amdgcn_mfma_f32_16x16x32_bf16(fa[m], fb[n], acc[m][n], 0, 0, 0);
  }
#pragma unroll
  for (int m = 0; m < 4; ++m) {
#pragma unroll
    for (int r = 0; r < 4; ++r) {
      const int row = m0 + wm + m * 16 + 4 * g + r;
#pragma unroll
      for (int n = 0; n < 4; ++n) {
        const int col = n0 + wn + n * 16 + c;
        float v = acc[m][n][r];
        if constexpr (ADD_RES) v += resid[(long)row * N + col];
        if constexpr (OUT_BF16)
          ((unsigned short*)Cout)[(long)row * N + col] = f2bf(v);
        else
          ((float*)Cout)[(long)row * N + col] = v;
      }
    }
  }
}

// ---------------- RoPE tables -----------------------------------------------
__global__ void rope_tables_kernel(float* __restrict__ cost, float* __restrict__ sint) {
  const int idx = blockIdx.x * 256 + threadIdx.x;  // T*64
  const int t = idx >> 6, i = idx & 63;
  const float invf = powf(10000.0f, -(float)i * (1.0f / 64.0f));
  const float ang = (float)t * invf;
  cost[idx] = cosf(ang);
  sint[idx] = sinf(ang);
}

// ---------------- RoPE apply in-place on q,k halves of qkv(bf16) ------------
__global__ __launch_bounds__(256) void rope_apply_kernel(
    unsigned short* __restrict__ qkv, const float* __restrict__ cost,
    const float* __restrict__ sint) {
  const long idx = (long)blockIdx.x * 256 + threadIdx.x;  // BT*16*64*2
  const int i = idx & 63;
  const int h = (idx >> 6) & 15;
  const int qk = (idx >> 10) & 1;
  const int row = idx >> 11;          // 0..BT-1
  const int t = row & (T_SEQ - 1);
  unsigned short* p = qkv + (long)row * (3 * D_MODEL) + qk * D_MODEL + h * D_HEAD + i;
  const float a = bf2f(p[0]);
  const float b = bf2f(p[64]);
  const float cv = cost[t * 64 + i];
  const float sv = sint[t * 64 + i];
  p[0] = f2bf(a * cv - b * sv);
  p[64] = f2bf(b * cv + a * sv);
}

// ---------------- V transpose: qkv v-part -> vt [B,H,128,T] bf16 ------------
__global__ __launch_bounds__(256) void vtrans_kernel(
    const unsigned short* __restrict__ qkv, unsigned short* __restrict__ vt) {
  __shared__ unsigned short tile[32][33];
  const int tx = threadIdx.x, ty = threadIdx.y;
  const int t0 = blockIdx.x * 32, d0 = blockIdx.y * 32;
  const int bh = blockIdx.z;  // b*16+h
  const int b = bh >> 4, h = bh & 15;
#pragma unroll
  for (int i = 0; i < 4; ++i)
    tile[ty + 8 * i][tx] =
        qkv[(long)(b * T_SEQ + t0 + ty + 8 * i) * (3 * D_MODEL) + 2 * D_MODEL + h * D_HEAD + d0 + tx];
  __syncthreads();
#pragma unroll
  for (int i = 0; i < 4; ++i)
    vt[((long)bh * D_HEAD + d0 + ty + 8 * i) * T_SEQ + t0 + tx] = tile[tx][ty + 8 * i];
}

// ---------------- Flash attention (causal), swapped-QK^T --------------------
// grid: (T/64, H, B); block 256 = 4 waves x 16 q-rows each.
__global__ __launch_bounds__(256) void attn_kernel(
    const unsigned short* __restrict__ qkv, const unsigned short* __restrict__ vt,
    unsigned short* __restrict__ ctx) {
  const int qt = blockIdx.x, h = blockIdx.y, b = blockIdx.z;
  const int tid = threadIdx.x;
  const int w = tid >> 6, lane = tid & 63, g = lane >> 4, c = lane & 15;
  const int qbase = qt * 64;
  const int q = qbase + w * 16 + c;  // this lane's q-column
  const float scale = 0.08838834764831845f;  // 128^-0.5

  bf16x8 fq[4];
  const long rowQ = (long)(b * T_SEQ + q) * (3 * D_MODEL) + h * D_HEAD;
#pragma unroll
  for (int ks = 0; ks < 4; ++ks)
    fq[ks] = *(const bf16x8*)(qkv + rowQ + ks * 32 + g * 8);

  f32x4 o[8] = {};
  float mrun = -INFINITY, ell = 0.0f;
  const int srcA = (2 * (g & 1)) * 16 + c;
  const int srcB = srcA + 16;
  const bool hi = (g >> 1) != 0;
  const long vtbase = (long)(b * N_HEADS + h) * D_HEAD * T_SEQ;

  for (int kt = 0; kt <= qt; ++kt) {
    const int kv0 = kt * 64;
    // S^T[64 kp][16 q] = K-tile · Q^T
    f32x4 s[4] = {};
#pragma unroll
    for (int fm = 0; fm < 4; ++fm) {
      const long rowK = (long)(b * T_SEQ + kv0 + fm * 16 + c) * (3 * D_MODEL) + D_MODEL + h * D_HEAD;
#pragma unroll
      for (int ks = 0; ks < 4; ++ks) {
        bf16x8 ak = *(const bf16x8*)(qkv + rowK + ks * 32 + g * 8);
        s[fm] = __builtin_amdgcn_mfma_f32_16x16x32_bf16(ak, fq[ks], s[fm], 0, 0, 0);
      }
    }
    // scale + causal mask + online softmax stats
    float pmax = -INFINITY;
    const bool diag = (kt == qt);
#pragma unroll
    for (int fm = 0; fm < 4; ++fm)
#pragma unroll
      for (int r = 0; r < 4; ++r) {
        float sv = s[fm][r] * scale;
        if (diag) {
          const int kp = kv0 + fm * 16 + 4 * g + r;
          if (kp > q) sv = -INFINITY;
        }
        s[fm][r] = sv;
        pmax = fmaxf(pmax, sv);
      }
    pmax = fmaxf(pmax, __shfl_xor(pmax, 16));
    pmax = fmaxf(pmax, __shfl_xor(pmax, 32));
    const float mnew = fmaxf(mrun, pmax);
    const float resc = __expf(mrun - mnew);
    mrun = mnew;
    float rowsum = 0.0f;
#pragma unroll
    for (int fm = 0; fm < 4; ++fm)
#pragma unroll
      for (int r = 0; r < 4; ++r) {
        const float p = __expf(s[fm][r] - mnew);
        s[fm][r] = p;
        rowsum += p;
      }
    rowsum += __shfl_xor(rowsum, 16);
    rowsum += __shfl_xor(rowsum, 32);
    ell = ell * resc + rowsum;
#pragma unroll
    for (int fm = 0; fm < 8; ++fm) o[fm] *= resc;

    // Redistribute P (S^T layout) -> P^T B-fragments via shuffles
    bf16x8 pb[2];
#pragma unroll
    for (int k2 = 0; k2 < 2; ++k2) {
      float va[4], vb[4];
#pragma unroll
      for (int r = 0; r < 4; ++r) {
        const float t0 = __shfl(s[k2 * 2][r], srcA);
        const float t1 = __shfl(s[k2 * 2 + 1][r], srcA);
        va[r] = hi ? t1 : t0;
        const float u0 = __shfl(s[k2 * 2][r], srcB);
        const float u1 = __shfl(s[k2 * 2 + 1][r], srcB);
        vb[r] = hi ? u1 : u0;
      }
      bf16x8 pv;
      pv[0] = (__bf16)va[0]; pv[1] = (__bf16)va[1];
      pv[2] = (__bf16)va[2]; pv[3] = (__bf16)va[3];
      pv[4] = (__bf16)vb[0]; pv[5] = (__bf16)vb[1];
      pv[6] = (__bf16)vb[2]; pv[7] = (__bf16)vb[3];
      pb[k2] = pv;
    }
    // O^T[128 d][16 q] += V^T · P^T
#pragma unroll
    for (int fm = 0; fm < 8; ++fm) {
#pragma unroll
      for (int k2 = 0; k2 < 2; ++k2) {
        bf16x8 av = *(const bf16x8*)(vt + vtbase + (long)(fm * 16 + c) * T_SEQ + kv0 + k2 * 32 + g * 8);
        o[fm] = __builtin_amdgcn_mfma_f32_16x16x32_bf16(av, pb[k2], o[fm], 0, 0, 0);
      }
    }
  }
  const float inv = 1.0f / ell;
  unsigned short* outp = ctx + (long)(b * T_SEQ + q) * D_MODEL + h * D_HEAD;
#pragma unroll
  for (int fm = 0; fm < 8; ++fm) {
    ushort4 pk;
    pk.x = f2bf(o[fm][0] * inv);
    pk.y = f2bf(o[fm][1] * inv);
    pk.z = f2bf(o[fm][2] * inv);
    pk.w = f2bf(o[fm][3] * inv);
    *(ushort4*)(outp + fm * 16 + 4 * g) = pk;
  }
}

// ---------------- SwiGLU: g = silu(g) * u (bf16, in-place on g) -------------
__global__ __launch_bounds__(256) void silu_mul_kernel(
    unsigned short* __restrict__ gb, const unsigned short* __restrict__ ub) {
  const long i = ((long)blockIdx.x * 256 + threadIdx.x) * 8;
  u16x8 gv = *(const u16x8*)(gb + i);
  u16x8 uv = *(const u16x8*)(ub + i);
  u16x8 r;
#pragma unroll
  for (int j = 0; j < 8; ++j) {
    const float gf = bf2f(gv[j]);
    const float uf = bf2f(uv[j]);
    const float s = gf / (1.0f + __expf(-gf));
    r[j] = f2bf(s * uf);
  }
  *(u16x8*)(gb + i) = r;
}

// ---------------------------------------------------------------------------
// Workspace budget (~236 MB total, aliased):
//   Wreg  100.7 MB : phase A = wTqkv(25.2)+wTout(8.4); phase B = wTg+wTu+wTo
//   AR     83.9 MB : phase A = qkvb(50.3)+vtb(16.8)+ctxb(16.8);
//                    phase B = gbuf(33.6)+ubuf(33.6) per 2048-row MLP chunk
//   x1     33.6 MB   (fp32 residual stream after attention)
//   hb     16.8 MB   (rmsnorm output, reused)
//   tables  1.0 MB
extern "C" void kernel_launch(void* const* d_in, const int* in_sizes, int n_in,
                              void* d_out, int out_size, void* d_ws, size_t ws_size,
                              hipStream_t stream) {
  const float* x = (const float*)d_in[0];
  const float* w_qkv = (const float*)d_in[1];
  const float* w_out = (const float*)d_in[2];
  const float* g1 = (const float*)d_in[3];
  const float* g2 = (const float*)d_in[4];
  const float* w_g = (const float*)d_in[5];
  const float* w_u = (const float*)d_in[6];
  const float* w_o = (const float*)d_in[7];
  float* out = (float*)d_out;

  char* ws = (char*)d_ws;
  size_t off = 0;
  auto take = [&](size_t bytes) {
    char* p = ws + off;
    off += (bytes + 255) & ~(size_t)255;
    return p;
  };

  // weight region (phase A and phase B alias the same memory)
  char* Wreg = take((size_t)3 * D_FF * D_MODEL * 2);  // 100.66 MB
  unsigned short* wTqkv = (unsigned short*)Wreg;                                   // 25.2 MB
  unsigned short* wTout = (unsigned short*)(Wreg + (size_t)3 * D_MODEL * D_MODEL * 2);  // 8.4 MB
  unsigned short* wTg = (unsigned short*)Wreg;
  unsigned short* wTu = (unsigned short*)(Wreg + (size_t)D_FF * D_MODEL * 2);
  unsigned short* wTo = (unsigned short*)(Wreg + (size_t)2 * D_FF * D_MODEL * 2);

  // activation region (phase A and phase B alias the same memory)
  const size_t qkv_b = (size_t)BT * 3 * D_MODEL * 2;                      // 50.3 MB
  const size_t vt_b = (size_t)B_SZ * N_HEADS * D_HEAD * T_SEQ * 2;        // 16.8 MB
  const size_t ctx_b = (size_t)BT * D_MODEL * 2;                          // 16.8 MB
  char* AR = take(qkv_b + vt_b + ctx_b);                                  // 83.9 MB
  unsigned short* qkvb = (unsigned short*)AR;
  unsigned short* vtb = (unsigned short*)(AR + qkv_b);
  unsigned short* ctxb = (unsigned short*)(AR + qkv_b + vt_b);
  unsigned short* gbuf = (unsigned short*)AR;                                    // 33.6 MB (chunk)
  unsigned short* ubuf = (unsigned short*)(AR + (size_t)MLP_CHUNK * D_FF * 2);   // 33.6 MB (chunk)

  float* x1 = (float*)take((size_t)BT * D_MODEL * 4);
  unsigned short* hb = (unsigned short*)take((size_t)BT * D_MODEL * 2);
  float* cost = (float*)take((size_t)T_SEQ * 64 * 4);
  float* sint = (float*)take((size_t)T_SEQ * 64 * 4);

  const dim3 tb(32, 8);

  // ---- phase A: attention ----
  transpose_cast_kernel<<<dim3(3 * D_MODEL / 32, D_MODEL / 32), tb, 0, stream>>>(w_qkv, wTqkv, D_MODEL, 3 * D_MODEL);
  transpose_cast_kernel<<<dim3(D_MODEL / 32, D_MODEL / 32), tb, 0, stream>>>(w_out, wTout, D_MODEL, D_MODEL);
  rope_tables_kernel<<<T_SEQ * 64 / 256, 256, 0, stream>>>(cost, sint);

  rmsnorm_cast_kernel<<<BT, 256, 0, stream>>>(x, g1, hb);
  gemm_bt_kernel<true, false><<<dim3(3 * D_MODEL / 128, BT / 128), 256, 0, stream>>>(
      hb, wTqkv, qkvb, nullptr, BT, 3 * D_MODEL, D_MODEL);
  rope_apply_kernel<<<(BT * N_HEADS * 64 * 2) / 256, 256, 0, stream>>>(qkvb, cost, sint);
  vtrans_kernel<<<dim3(T_SEQ / 32, D_HEAD / 32, B_SZ * N_HEADS), tb, 0, stream>>>(qkvb, vtb);
  attn_kernel<<<dim3(T_SEQ / 64, N_HEADS, B_SZ), 256, 0, stream>>>(qkvb, vtb, ctxb);
  gemm_bt_kernel<false, true><<<dim3(D_MODEL / 128, BT / 128), 256, 0, stream>>>(
      ctxb, wTout, x1, x, BT, D_MODEL, D_MODEL);

  // ---- phase B: MLP (weight region + activation region are re-used; all
  // consumers of the phase-A contents have already been enqueued above) ----
  transpose_cast_kernel<<<dim3(D_FF / 32, D_MODEL / 32), tb, 0, stream>>>(w_g, wTg, D_MODEL, D_FF);
  transpose_cast_kernel<<<dim3(D_FF / 32, D_MODEL / 32), tb, 0, stream>>>(w_u, wTu, D_MODEL, D_FF);
  transpose_cast_kernel<<<dim3(D_MODEL / 32, D_FF / 32), tb, 0, stream>>>(w_o, wTo, D_FF, D_MODEL);
  rmsnorm_cast_kernel<<<BT, 256, 0, stream>>>(x1, g2, hb);

  for (int chunk = 0; chunk < BT / MLP_CHUNK; ++chunk) {
    const long r0 = (long)chunk * MLP_CHUNK;
    gemm_bt_kernel<true, false><<<dim3(D_FF / 128, MLP_CHUNK / 128), 256, 0, stream>>>(
        hb + r0 * D_MODEL, wTg, gbuf, nullptr, MLP_CHUNK, D_FF, D_MODEL);
    gemm_bt_kernel<true, false><<<dim3(D_FF / 128, MLP_CHUNK / 128), 256, 0, stream>>>(
        hb + r0 * D_MODEL, wTu, ubuf, nullptr, MLP_CHUNK, D_FF, D_MODEL);
    silu_mul_kernel<<<(int)((long)MLP_CHUNK * D_FF / 8 / 256), 256, 0, stream>>>(gbuf, ubuf);
    gemm_bt_kernel<false, true><<<dim3(D_MODEL / 128, MLP_CHUNK / 128), 256, 0, stream>>>(
        gbuf, wTo, out + r0 * D_MODEL, x1 + r0 * D_MODEL, MLP_CHUNK, D_MODEL, D_FF);
  }
}

// Round 3
// 1202.490 us; speedup vs baseline: 1.3549x; 1.3549x over previous
//
#include <hip/hip_runtime.h>

typedef __bf16 bf16x8 __attribute__((ext_vector_type(8)));
typedef float f32x4 __attribute__((ext_vector_type(4)));
typedef unsigned short u16x8 __attribute__((ext_vector_type(8)));

#define B_SZ 2
#define T_SEQ 2048
#define D_MODEL 2048
#define N_HEADS 16
#define D_HEAD 128
#define D_FF 8192
#define BT (B_SZ * T_SEQ)
#define MLP_CHUNK 2048
#define NT (T_SEQ / 64)

__device__ __forceinline__ unsigned short f2bf(float f) {
  unsigned int u = __builtin_bit_cast(unsigned int, f);
  u += 0x7FFFu + ((u >> 16) & 1u);
  return (unsigned short)(u >> 16);
}
__device__ __forceinline__ float bf2f(unsigned short h) {
  unsigned int u = ((unsigned int)h) << 16;
  return __builtin_bit_cast(float, u);
}

__device__ __forceinline__ void load_lds16(const void* g, void* l) {
  __builtin_amdgcn_global_load_lds(
      (const __attribute__((address_space(1))) unsigned int*)g,
      (__attribute__((address_space(3))) unsigned int*)l, 16, 0, 0);
}

// ---------------- transpose + cast: in fp32 [R][C] -> out bf16 [C][R] -------
__global__ __launch_bounds__(256) void transpose_cast_kernel(
    const float* __restrict__ in, unsigned short* __restrict__ out, int R, int C) {
  __shared__ float tile[32][33];
  const int tx = threadIdx.x, ty = threadIdx.y;
  const int c0 = blockIdx.x * 32, r0 = blockIdx.y * 32;
#pragma unroll
  for (int i = 0; i < 4; ++i)
    tile[ty + 8 * i][tx] = in[(long)(r0 + ty + 8 * i) * C + c0 + tx];
  __syncthreads();
#pragma unroll
  for (int i = 0; i < 4; ++i)
    out[(long)(c0 + ty + 8 * i) * R + r0 + tx] = f2bf(tile[tx][ty + 8 * i]);
}

// ---------------- RMSNorm fp32 row -> bf16 ----------------------------------
__global__ __launch_bounds__(256) void rmsnorm_cast_kernel(
    const float* __restrict__ x, const float* __restrict__ gw,
    unsigned short* __restrict__ out) {
  const int row = blockIdx.x;
  const int tid = threadIdx.x;
  const float* xr = x + (long)row * D_MODEL;
  float4 a = *(const float4*)(xr + tid * 8);
  float4 b = *(const float4*)(xr + tid * 8 + 4);
  float ss = a.x * a.x + a.y * a.y + a.z * a.z + a.w * a.w +
             b.x * b.x + b.y * b.y + b.z * b.z + b.w * b.w;
#pragma unroll
  for (int d = 1; d < 64; d <<= 1) ss += __shfl_xor(ss, d);
  __shared__ float part[4];
  if ((tid & 63) == 0) part[tid >> 6] = ss;
  __syncthreads();
  ss = part[0] + part[1] + part[2] + part[3];
  const float rs = rsqrtf(ss * (1.0f / D_MODEL) + 1e-6f);
  float4 g0 = *(const float4*)(gw + tid * 8);
  float4 g1 = *(const float4*)(gw + tid * 8 + 4);
  ushort4 o0, o1;
  o0.x = f2bf(a.x * rs * g0.x); o0.y = f2bf(a.y * rs * g0.y);
  o0.z = f2bf(a.z * rs * g0.z); o0.w = f2bf(a.w * rs * g0.w);
  o1.x = f2bf(b.x * rs * g1.x); o1.y = f2bf(b.y * rs * g1.y);
  o1.z = f2bf(b.z * rs * g1.z); o1.w = f2bf(b.w * rs * g1.w);
  unsigned short* op = out + (long)row * D_MODEL + tid * 8;
  *(ushort4*)op = o0;
  *(ushort4*)(op + 4) = o1;
}

// ---------------- GEMM: C[M,N] = A[M,K](bf16) @ Bt[N,K](bf16)^T -------------
// m97-style: 128x128 tile, BK=32, 4 waves, global_load_lds staging.
template <bool OUT_BF16, bool ADD_RES>
__global__ __launch_bounds__(256) void gemm_bt_kernel(
    const unsigned short* __restrict__ A, const unsigned short* __restrict__ Bt,
    void* __restrict__ Cout, const float* __restrict__ resid,
    int M, int N, int K) {
  __shared__ unsigned short As[128 * 32];
  __shared__ unsigned short Bs[128 * 32];
  const int tid = threadIdx.x;
  const int w = tid >> 6, lane = tid & 63, g = lane >> 4, c = lane & 15;
  const int m0 = blockIdx.y * 128, n0 = blockIdx.x * 128;
  const int wm = (w >> 1) * 64, wn = (w & 1) * 64;
  const int srow = lane >> 2;        // 16 rows per 1KB chunk
  const int scol = (lane & 3) * 8;   // 4 lanes x 8 bf16 per row
  const int ch0 = w * 2;
  f32x4 acc[4][4] = {};
  const int nkt = K >> 5;
  const unsigned short* Abase = A + (long)m0 * K + scol;
  const unsigned short* Bbase = Bt + (long)n0 * K + scol;
  for (int kt = 0; kt < nkt; ++kt) {
    __syncthreads();
#pragma unroll
    for (int i = 0; i < 2; ++i) {
      const int ch = ch0 + i;
      load_lds16(Abase + (long)(ch * 16 + srow) * K + kt * 32, &As[ch * 512]);
      load_lds16(Bbase + (long)(ch * 16 + srow) * K + kt * 32, &Bs[ch * 512]);
    }
    __syncthreads();
    bf16x8 fa[4], fb[4];
#pragma unroll
    for (int m = 0; m < 4; ++m)
      fa[m] = *(const bf16x8*)(As + (wm + m * 16 + c) * 32 + g * 8);
#pragma unroll
    for (int n = 0; n < 4; ++n)
      fb[n] = *(const bf16x8*)(Bs + (wn + n * 16 + c) * 32 + g * 8);
#pragma unroll
    for (int m = 0; m < 4; ++m)
#pragma unroll
      for (int n = 0; n < 4; ++n)
        acc[m][n] = __builtin_amdgcn_mfma_f32_16x16x32_bf16(fa[m], fb[n], acc[m][n], 0, 0, 0);
  }
#pragma unroll
  for (int m = 0; m < 4; ++m) {
#pragma unroll
    for (int r = 0; r < 4; ++r) {
      const int row = m0 + wm + m * 16 + 4 * g + r;
#pragma unroll
      for (int n = 0; n < 4; ++n) {
        const int col = n0 + wn + n * 16 + c;
        float v = acc[m][n][r];
        if constexpr (ADD_RES) v += resid[(long)row * N + col];
        if constexpr (OUT_BF16)
          ((unsigned short*)Cout)[(long)row * N + col] = f2bf(v);
        else
          ((float*)Cout)[(long)row * N + col] = v;
      }
    }
  }
}

// ---------------- RoPE tables -----------------------------------------------
__global__ void rope_tables_kernel(float* __restrict__ cost, float* __restrict__ sint) {
  const int idx = blockIdx.x * 256 + threadIdx.x;  // T*64
  const int t = idx >> 6, i = idx & 63;
  const float invf = powf(10000.0f, -(float)i * (1.0f / 64.0f));
  const float ang = (float)t * invf;
  cost[idx] = cosf(ang);
  sint[idx] = sinf(ang);
}

// ---------------- RoPE apply in-place on q,k halves of qkv(bf16) ------------
__global__ __launch_bounds__(256) void rope_apply_kernel(
    unsigned short* __restrict__ qkv, const float* __restrict__ cost,
    const float* __restrict__ sint) {
  const long idx = (long)blockIdx.x * 256 + threadIdx.x;  // BT*16*64*2
  const int i = idx & 63;
  const int h = (idx >> 6) & 15;
  const int qk = (idx >> 10) & 1;
  const int row = idx >> 11;          // 0..BT-1
  const int t = row & (T_SEQ - 1);
  unsigned short* p = qkv + (long)row * (3 * D_MODEL) + qk * D_MODEL + h * D_HEAD + i;
  const float a = bf2f(p[0]);
  const float b = bf2f(p[64]);
  const float cv = cost[t * 64 + i];
  const float sv = sint[t * 64 + i];
  p[0] = f2bf(a * cv - b * sv);
  p[64] = f2bf(b * cv + a * sv);
}

// ---------------- V transpose: qkv v-part -> vt [B,H,128,T] bf16 ------------
__global__ __launch_bounds__(256) void vtrans_kernel(
    const unsigned short* __restrict__ qkv, unsigned short* __restrict__ vt) {
  __shared__ unsigned short tile[32][33];
  const int tx = threadIdx.x, ty = threadIdx.y;
  const int t0 = blockIdx.x * 32, d0 = blockIdx.y * 32;
  const int bh = blockIdx.z;  // b*16+h
  const int b = bh >> 4, h = bh & 15;
#pragma unroll
  for (int i = 0; i < 4; ++i)
    tile[ty + 8 * i][tx] =
        qkv[(long)(b * T_SEQ + t0 + ty + 8 * i) * (3 * D_MODEL) + 2 * D_MODEL + h * D_HEAD + d0 + tx];
  __syncthreads();
#pragma unroll
  for (int i = 0; i < 4; ++i)
    vt[((long)bh * D_HEAD + d0 + ty + 8 * i) * T_SEQ + t0 + tx] = tile[tx][ty + 8 * i];
}

// ---------------- Flash attention (causal), swapped-QK^T --------------------
// grid: (NT/2, H, B); block 256 = 4 waves x 16 q-rows.
// Each block handles the balanced q-tile pair {qt, NT-1-qt} (33 kt-iters).
// K and V tiles are LDS-staged (shared by all 4 waves), double-buffered,
// XOR-swizzled (linear LDS dest + pre-swizzled global src + swizzled read).
__global__ __launch_bounds__(256) void attn_kernel(
    const unsigned short* __restrict__ qkv, const unsigned short* __restrict__ vt,
    unsigned short* __restrict__ ctx) {
  __shared__ unsigned short Ks[2][64 * 128];   // [kp 64][d 128], 16KB each buf
  __shared__ unsigned short Vs[2][128 * 64];   // [d 128][t 64], 16KB each buf
  const int h = blockIdx.y, b = blockIdx.z;
  const int tid = threadIdx.x;
  const int w = tid >> 6, lane = tid & 63, g = lane >> 4, c = lane & 15;
  const float scale = 0.08838834764831845f;  // 128^-0.5
  const int srcA = (2 * (g & 1)) * 16 + c;
  const int srcB = srcA + 16;
  const bool hi = (g >> 1) != 0;
  const int bh = b * N_HEADS + h;

  // staging: 1024 16B-slots per tile, 4 per thread; source col pre-swizzled
  const int ssk = (tid & 15) ^ ((tid >> 4) & 7);  // K slot-col (16 per row)
  const int ssv = (tid & 7) ^ ((tid >> 3) & 7);   // V slot-col (8 per row)
  const unsigned short* Kg = qkv + (long)b * T_SEQ * 3 * D_MODEL + D_MODEL + (long)h * D_HEAD;
  const unsigned short* Vg = vt + (long)bh * D_HEAD * T_SEQ;

  auto stage = [&](int kv0, int bufi) {
#pragma unroll
    for (int i = 0; i < 4; ++i) {
      const int rowk = i * 16 + (tid >> 4);
      load_lds16(Kg + (long)(kv0 + rowk) * (3 * D_MODEL) + ssk * 8,
                 &Ks[bufi][(i * 256 + tid) * 8]);
    }
#pragma unroll
    for (int i = 0; i < 4; ++i) {
      const int rowv = i * 32 + (tid >> 3);
      load_lds16(Vg + (long)rowv * T_SEQ + kv0 + ssv * 8,
                 &Vs[bufi][(i * 256 + tid) * 8]);
    }
  };

  const int cs7 = c & 7;

  for (int pass = 0; pass < 2; ++pass) {
    const int qt = pass ? (NT - 1 - blockIdx.x) : blockIdx.x;
    const int q = qt * 64 + w * 16 + c;

    bf16x8 fq[4];
    const long rowQ = (long)(b * T_SEQ + q) * (3 * D_MODEL) + h * D_HEAD;
#pragma unroll
    for (int ks = 0; ks < 4; ++ks)
      fq[ks] = *(const bf16x8*)(qkv + rowQ + ks * 32 + g * 8);

    f32x4 o[8] = {};
    float mrun = -INFINITY, ell = 0.0f;

    stage(0, 0);
    asm volatile("s_waitcnt vmcnt(0)" ::: "memory");
    __syncthreads();
    int buf = 0;

    for (int kt = 0; kt <= qt; ++kt) {
      const int kv0 = kt * 64;
      if (kt < qt) stage(kv0 + 64, buf ^ 1);  // prefetch next tile

      // S^T[64 kp][16 q] = K-tile · Q^T  (K from LDS, swizzled read)
      f32x4 s[4] = {};
#pragma unroll
      for (int fm = 0; fm < 4; ++fm) {
        const unsigned short* kr = &Ks[buf][(fm * 16 + c) * 128];
#pragma unroll
        for (int ks = 0; ks < 4; ++ks) {
          bf16x8 ak = *(const bf16x8*)(kr + ((ks * 4 + g) ^ cs7) * 8);
          s[fm] = __builtin_amdgcn_mfma_f32_16x16x32_bf16(ak, fq[ks], s[fm], 0, 0, 0);
        }
      }
      // scale + causal mask + online softmax stats
      float pmax = -INFINITY;
      const bool diag = (kt == qt);
#pragma unroll
      for (int fm = 0; fm < 4; ++fm)
#pragma unroll
        for (int r = 0; r < 4; ++r) {
          float sv = s[fm][r] * scale;
          if (diag) {
            const int kp = kv0 + fm * 16 + 4 * g + r;
            if (kp > q) sv = -INFINITY;
          }
          s[fm][r] = sv;
          pmax = fmaxf(pmax, sv);
        }
      pmax = fmaxf(pmax, __shfl_xor(pmax, 16));
      pmax = fmaxf(pmax, __shfl_xor(pmax, 32));
      const float mnew = fmaxf(mrun, pmax);
      const float resc = __expf(mrun - mnew);
      mrun = mnew;
      float rowsum = 0.0f;
#pragma unroll
      for (int fm = 0; fm < 4; ++fm)
#pragma unroll
        for (int r = 0; r < 4; ++r) {
          const float p = __expf(s[fm][r] - mnew);
          s[fm][r] = p;
          rowsum += p;
        }
      rowsum += __shfl_xor(rowsum, 16);
      rowsum += __shfl_xor(rowsum, 32);
      ell = ell * resc + rowsum;
#pragma unroll
      for (int fm = 0; fm < 8; ++fm) o[fm] *= resc;

      // Redistribute P (S^T layout) -> P^T B-fragments via shuffles
      bf16x8 pb[2];
#pragma unroll
      for (int k2 = 0; k2 < 2; ++k2) {
        float va[4], vb[4];
#pragma unroll
        for (int r = 0; r < 4; ++r) {
          const float t0 = __shfl(s[k2 * 2][r], srcA);
          const float t1 = __shfl(s[k2 * 2 + 1][r], srcA);
          va[r] = hi ? t1 : t0;
          const float u0 = __shfl(s[k2 * 2][r], srcB);
          const float u1 = __shfl(s[k2 * 2 + 1][r], srcB);
          vb[r] = hi ? u1 : u0;
        }
        bf16x8 pv;
        pv[0] = (__bf16)va[0]; pv[1] = (__bf16)va[1];
        pv[2] = (__bf16)va[2]; pv[3] = (__bf16)va[3];
        pv[4] = (__bf16)vb[0]; pv[5] = (__bf16)vb[1];
        pv[6] = (__bf16)vb[2]; pv[7] = (__bf16)vb[3];
        pb[k2] = pv;
      }
      // O^T[128 d][16 q] += V^T · P^T  (V from LDS, swizzled read)
#pragma unroll
      for (int fm = 0; fm < 8; ++fm) {
        const unsigned short* vr = &Vs[buf][(fm * 16 + c) * 64];
#pragma unroll
        for (int k2 = 0; k2 < 2; ++k2) {
          bf16x8 av = *(const bf16x8*)(vr + ((k2 * 4 + g) ^ cs7) * 8);
          o[fm] = __builtin_amdgcn_mfma_f32_16x16x32_bf16(av, pb[k2], o[fm], 0, 0, 0);
        }
      }
      asm volatile("s_waitcnt vmcnt(0)" ::: "memory");
      __syncthreads();
      buf ^= 1;
    }

    const float inv = 1.0f / ell;
    unsigned short* outp = ctx + (long)(b * T_SEQ + q) * D_MODEL + h * D_HEAD;
#pragma unroll
    for (int fm = 0; fm < 8; ++fm) {
      ushort4 pk;
      pk.x = f2bf(o[fm][0] * inv);
      pk.y = f2bf(o[fm][1] * inv);
      pk.z = f2bf(o[fm][2] * inv);
      pk.w = f2bf(o[fm][3] * inv);
      *(ushort4*)(outp + fm * 16 + 4 * g) = pk;
    }
  }
}

// ---------------- SwiGLU: g = silu(g) * u (bf16, in-place on g) -------------
__global__ __launch_bounds__(256) void silu_mul_kernel(
    unsigned short* __restrict__ gb, const unsigned short* __restrict__ ub) {
  const long i = ((long)blockIdx.x * 256 + threadIdx.x) * 8;
  u16x8 gv = *(const u16x8*)(gb + i);
  u16x8 uv = *(const u16x8*)(ub + i);
  u16x8 r;
#pragma unroll
  for (int j = 0; j < 8; ++j) {
    const float gf = bf2f(gv[j]);
    const float uf = bf2f(uv[j]);
    const float s = gf / (1.0f + __expf(-gf));
    r[j] = f2bf(s * uf);
  }
  *(u16x8*)(gb + i) = r;
}

// ---------------------------------------------------------------------------
// Workspace budget (~236 MB total, aliased):
//   Wreg  100.7 MB : phase A = wTqkv(25.2)+wTout(8.4); phase B = wTg+wTu+wTo
//   AR     83.9 MB : phase A = qkvb(50.3)+vtb(16.8)+ctxb(16.8);
//                    phase B = gbuf(33.6)+ubuf(33.6) per 2048-row MLP chunk
//   x1     33.6 MB   (fp32 residual stream after attention)
//   hb     16.8 MB   (rmsnorm output, reused)
//   tables  1.0 MB
extern "C" void kernel_launch(void* const* d_in, const int* in_sizes, int n_in,
                              void* d_out, int out_size, void* d_ws, size_t ws_size,
                              hipStream_t stream) {
  const float* x = (const float*)d_in[0];
  const float* w_qkv = (const float*)d_in[1];
  const float* w_out = (const float*)d_in[2];
  const float* g1 = (const float*)d_in[3];
  const float* g2 = (const float*)d_in[4];
  const float* w_g = (const float*)d_in[5];
  const float* w_u = (const float*)d_in[6];
  const float* w_o = (const float*)d_in[7];
  float* out = (float*)d_out;

  char* ws = (char*)d_ws;
  size_t off = 0;
  auto take = [&](size_t bytes) {
    char* p = ws + off;
    off += (bytes + 255) & ~(size_t)255;
    return p;
  };

  // weight region (phase A and phase B alias the same memory)
  char* Wreg = take((size_t)3 * D_FF * D_MODEL * 2);  // 100.66 MB
  unsigned short* wTqkv = (unsigned short*)Wreg;                                   // 25.2 MB
  unsigned short* wTout = (unsigned short*)(Wreg + (size_t)3 * D_MODEL * D_MODEL * 2);  // 8.4 MB
  unsigned short* wTg = (unsigned short*)Wreg;
  unsigned short* wTu = (unsigned short*)(Wreg + (size_t)D_FF * D_MODEL * 2);
  unsigned short* wTo = (unsigned short*)(Wreg + (size_t)2 * D_FF * D_MODEL * 2);

  // activation region (phase A and phase B alias the same memory)
  const size_t qkv_b = (size_t)BT * 3 * D_MODEL * 2;                      // 50.3 MB
  const size_t vt_b = (size_t)B_SZ * N_HEADS * D_HEAD * T_SEQ * 2;        // 16.8 MB
  const size_t ctx_b = (size_t)BT * D_MODEL * 2;                          // 16.8 MB
  char* AR = take(qkv_b + vt_b + ctx_b);                                  // 83.9 MB
  unsigned short* qkvb = (unsigned short*)AR;
  unsigned short* vtb = (unsigned short*)(AR + qkv_b);
  unsigned short* ctxb = (unsigned short*)(AR + qkv_b + vt_b);
  unsigned short* gbuf = (unsigned short*)AR;                                    // 33.6 MB (chunk)
  unsigned short* ubuf = (unsigned short*)(AR + (size_t)MLP_CHUNK * D_FF * 2);   // 33.6 MB (chunk)

  float* x1 = (float*)take((size_t)BT * D_MODEL * 4);
  unsigned short* hb = (unsigned short*)take((size_t)BT * D_MODEL * 2);
  float* cost = (float*)take((size_t)T_SEQ * 64 * 4);
  float* sint = (float*)take((size_t)T_SEQ * 64 * 4);

  const dim3 tb(32, 8);

  // ---- phase A: attention ----
  transpose_cast_kernel<<<dim3(3 * D_MODEL / 32, D_MODEL / 32), tb, 0, stream>>>(w_qkv, wTqkv, D_MODEL, 3 * D_MODEL);
  transpose_cast_kernel<<<dim3(D_MODEL / 32, D_MODEL / 32), tb, 0, stream>>>(w_out, wTout, D_MODEL, D_MODEL);
  rope_tables_kernel<<<T_SEQ * 64 / 256, 256, 0, stream>>>(cost, sint);

  rmsnorm_cast_kernel<<<BT, 256, 0, stream>>>(x, g1, hb);
  gemm_bt_kernel<true, false><<<dim3(3 * D_MODEL / 128, BT / 128), 256, 0, stream>>>(
      hb, wTqkv, qkvb, nullptr, BT, 3 * D_MODEL, D_MODEL);
  rope_apply_kernel<<<(BT * N_HEADS * 64 * 2) / 256, 256, 0, stream>>>(qkvb, cost, sint);
  vtrans_kernel<<<dim3(T_SEQ / 32, D_HEAD / 32, B_SZ * N_HEADS), tb, 0, stream>>>(qkvb, vtb);
  attn_kernel<<<dim3(NT / 2, N_HEADS, B_SZ), 256, 0, stream>>>(qkvb, vtb, ctxb);
  gemm_bt_kernel<false, true><<<dim3(D_MODEL / 128, BT / 128), 256, 0, stream>>>(
      ctxb, wTout, x1, x, BT, D_MODEL, D_MODEL);

  // ---- phase B: MLP (weight region + activation region are re-used; all
  // consumers of the phase-A contents have already been enqueued above) ----
  transpose_cast_kernel<<<dim3(D_FF / 32, D_MODEL / 32), tb, 0, stream>>>(w_g, wTg, D_MODEL, D_FF);
  transpose_cast_kernel<<<dim3(D_FF / 32, D_MODEL / 32), tb, 0, stream>>>(w_u, wTu, D_MODEL, D_FF);
  transpose_cast_kernel<<<dim3(D_MODEL / 32, D_FF / 32), tb, 0, stream>>>(w_o, wTo, D_FF, D_MODEL);
  rmsnorm_cast_kernel<<<BT, 256, 0, stream>>>(x1, g2, hb);

  for (int chunk = 0; chunk < BT / MLP_CHUNK; ++chunk) {
    const long r0 = (long)chunk * MLP_CHUNK;
    gemm_bt_kernel<true, false><<<dim3(D_FF / 128, MLP_CHUNK / 128), 256, 0, stream>>>(
        hb + r0 * D_MODEL, wTg, gbuf, nullptr, MLP_CHUNK, D_FF, D_MODEL);
    gemm_bt_kernel<true, false><<<dim3(D_FF / 128, MLP_CHUNK / 128), 256, 0, stream>>>(
        hb + r0 * D_MODEL, wTu, ubuf, nullptr, MLP_CHUNK, D_FF, D_MODEL);
    silu_mul_kernel<<<(int)((long)MLP_CHUNK * D_FF / 8 / 256), 256, 0, stream>>>(gbuf, ubuf);
    gemm_bt_kernel<false, true><<<dim3(D_MODEL / 128, MLP_CHUNK / 128), 256, 0, stream>>>(
        gbuf, wTo, out + r0 * D_MODEL, x1 + r0 * D_MODEL, MLP_CHUNK, D_MODEL, D_FF);
  }
}

// Round 4
// 1048.064 us; speedup vs baseline: 1.5546x; 1.1473x over previous
//
#include <hip/hip_runtime.h>

typedef __bf16 bf16x8 __attribute__((ext_vector_type(8)));
typedef float f32x4 __attribute__((ext_vector_type(4)));
typedef unsigned short u16x8 __attribute__((ext_vector_type(8)));

#define B_SZ 2
#define T_SEQ 2048
#define D_MODEL 2048
#define N_HEADS 16
#define D_HEAD 128
#define D_FF 8192
#define BT (B_SZ * T_SEQ)
#define NT (T_SEQ / 64)

__device__ __forceinline__ unsigned short f2bf(float f) {
  unsigned int u = __builtin_bit_cast(unsigned int, f);
  u += 0x7FFFu + ((u >> 16) & 1u);
  return (unsigned short)(u >> 16);
}
__device__ __forceinline__ float bf2f(unsigned short h) {
  unsigned int u = ((unsigned int)h) << 16;
  return __builtin_bit_cast(float, u);
}

__device__ __forceinline__ void load_lds16(const void* g, void* l) {
  __builtin_amdgcn_global_load_lds(
      (const __attribute__((address_space(1))) unsigned int*)g,
      (__attribute__((address_space(3))) unsigned int*)l, 16, 0, 0);
}

// ---------------- transpose + cast: in fp32 [R][C] -> out bf16 [C][R] -------
__global__ __launch_bounds__(256) void transpose_cast_kernel(
    const float* __restrict__ in, unsigned short* __restrict__ out, int R, int C) {
  __shared__ float tile[32][33];
  const int tx = threadIdx.x, ty = threadIdx.y;
  const int c0 = blockIdx.x * 32, r0 = blockIdx.y * 32;
#pragma unroll
  for (int i = 0; i < 4; ++i)
    tile[ty + 8 * i][tx] = in[(long)(r0 + ty + 8 * i) * C + c0 + tx];
  __syncthreads();
#pragma unroll
  for (int i = 0; i < 4; ++i)
    out[(long)(c0 + ty + 8 * i) * R + r0 + tx] = f2bf(tile[tx][ty + 8 * i]);
}

// ---------------- RMSNorm fp32 row -> bf16 ----------------------------------
__global__ __launch_bounds__(256) void rmsnorm_cast_kernel(
    const float* __restrict__ x, const float* __restrict__ gw,
    unsigned short* __restrict__ out) {
  const int row = blockIdx.x;
  const int tid = threadIdx.x;
  const float* xr = x + (long)row * D_MODEL;
  float4 a = *(const float4*)(xr + tid * 8);
  float4 b = *(const float4*)(xr + tid * 8 + 4);
  float ss = a.x * a.x + a.y * a.y + a.z * a.z + a.w * a.w +
             b.x * b.x + b.y * b.y + b.z * b.z + b.w * b.w;
#pragma unroll
  for (int d = 1; d < 64; d <<= 1) ss += __shfl_xor(ss, d);
  __shared__ float part[4];
  if ((tid & 63) == 0) part[tid >> 6] = ss;
  __syncthreads();
  ss = part[0] + part[1] + part[2] + part[3];
  const float rs = rsqrtf(ss * (1.0f / D_MODEL) + 1e-6f);
  float4 g0 = *(const float4*)(gw + tid * 8);
  float4 g1 = *(const float4*)(gw + tid * 8 + 4);
  ushort4 o0, o1;
  o0.x = f2bf(a.x * rs * g0.x); o0.y = f2bf(a.y * rs * g0.y);
  o0.z = f2bf(a.z * rs * g0.z); o0.w = f2bf(a.w * rs * g0.w);
  o1.x = f2bf(b.x * rs * g1.x); o1.y = f2bf(b.y * rs * g1.y);
  o1.z = f2bf(b.z * rs * g1.z); o1.w = f2bf(b.w * rs * g1.w);
  unsigned short* op = out + (long)row * D_MODEL + tid * 8;
  *(ushort4*)op = o0;
  *(ushort4*)(op + 4) = o1;
}

// ---------------- GEMM: C[M,N] = A[M,K](bf16) @ Bt[N,K](bf16)^T -------------
// m97-style: 128x128 tile, BK=32, 4 waves, global_load_lds staging.
// EPI: 0 = bf16 store; 1 = fp32 store + fp32 resid add; 2 = silu(acc)*aux(bf16)
template <int EPI>
__global__ __launch_bounds__(256) void gemm_bt_kernel(
    const unsigned short* __restrict__ A, const unsigned short* __restrict__ Bt,
    void* __restrict__ Cout, const void* __restrict__ aux,
    int M, int N, int K, int lda, int ldb, int ldc) {
  __shared__ unsigned short As[128 * 32];
  __shared__ unsigned short Bs[128 * 32];
  const int tid = threadIdx.x;
  const int w = tid >> 6, lane = tid & 63, g = lane >> 4, c = lane & 15;
  const int m0 = blockIdx.y * 128, n0 = blockIdx.x * 128;
  const int wm = (w >> 1) * 64, wn = (w & 1) * 64;
  const int srow = lane >> 2;        // 16 rows per 1KB chunk
  const int scol = (lane & 3) * 8;   // 4 lanes x 8 bf16 per row
  const int ch0 = w * 2;
  f32x4 acc[4][4] = {};
  const int nkt = K >> 5;
  const unsigned short* Abase = A + (long)m0 * lda + scol;
  const unsigned short* Bbase = Bt + (long)n0 * ldb + scol;
  for (int kt = 0; kt < nkt; ++kt) {
    __syncthreads();
#pragma unroll
    for (int i = 0; i < 2; ++i) {
      const int ch = ch0 + i;
      load_lds16(Abase + (long)(ch * 16 + srow) * lda + kt * 32, &As[ch * 512]);
      load_lds16(Bbase + (long)(ch * 16 + srow) * ldb + kt * 32, &Bs[ch * 512]);
    }
    __syncthreads();
    bf16x8 fa[4], fb[4];
#pragma unroll
    for (int m = 0; m < 4; ++m)
      fa[m] = *(const bf16x8*)(As + (wm + m * 16 + c) * 32 + g * 8);
#pragma unroll
    for (int n = 0; n < 4; ++n)
      fb[n] = *(const bf16x8*)(Bs + (wn + n * 16 + c) * 32 + g * 8);
#pragma unroll
    for (int m = 0; m < 4; ++m)
#pragma unroll
      for (int n = 0; n < 4; ++n)
        acc[m][n] = __builtin_amdgcn_mfma_f32_16x16x32_bf16(fa[m], fb[n], acc[m][n], 0, 0, 0);
  }
#pragma unroll
  for (int m = 0; m < 4; ++m) {
#pragma unroll
    for (int r = 0; r < 4; ++r) {
      const int row = m0 + wm + m * 16 + 4 * g + r;
#pragma unroll
      for (int n = 0; n < 4; ++n) {
        const int col = n0 + wn + n * 16 + c;
        const long idx = (long)row * ldc + col;
        float v = acc[m][n][r];
        if constexpr (EPI == 0) {
          ((unsigned short*)Cout)[idx] = f2bf(v);
        } else if constexpr (EPI == 1) {
          ((float*)Cout)[idx] = v + ((const float*)aux)[idx];
        } else {
          const float u = bf2f(((const unsigned short*)aux)[idx]);
          const float s = v / (1.0f + __expf(-v));
          ((unsigned short*)Cout)[idx] = f2bf(s * u);
        }
      }
    }
  }
}

// ---------------- RoPE tables -----------------------------------------------
__global__ void rope_tables_kernel(float* __restrict__ cost, float* __restrict__ sint) {
  const int idx = blockIdx.x * 256 + threadIdx.x;  // T*64
  const int t = idx >> 6, i = idx & 63;
  const float invf = powf(10000.0f, -(float)i * (1.0f / 64.0f));
  const float ang = (float)t * invf;
  cost[idx] = cosf(ang);
  sint[idx] = sinf(ang);
}

// ---------------- RoPE apply in-place on q,k halves of qkv(bf16) ------------
__global__ __launch_bounds__(256) void rope_apply_kernel(
    unsigned short* __restrict__ qkv, const float* __restrict__ cost,
    const float* __restrict__ sint) {
  const long idx = (long)blockIdx.x * 256 + threadIdx.x;  // BT*16*64*2
  const int i = idx & 63;
  const int h = (idx >> 6) & 15;
  const int qk = (idx >> 10) & 1;
  const int row = idx >> 11;          // 0..BT-1
  const int t = row & (T_SEQ - 1);
  unsigned short* p = qkv + (long)row * (3 * D_MODEL) + qk * D_MODEL + h * D_HEAD + i;
  const float a = bf2f(p[0]);
  const float b = bf2f(p[64]);
  const float cv = cost[t * 64 + i];
  const float sv = sint[t * 64 + i];
  p[0] = f2bf(a * cv - b * sv);
  p[64] = f2bf(b * cv + a * sv);
}

// ---------------- V transpose: qkv v-part -> vt [B,H,128,T] bf16 ------------
__global__ __launch_bounds__(256) void vtrans_kernel(
    const unsigned short* __restrict__ qkv, unsigned short* __restrict__ vt) {
  __shared__ unsigned short tile[32][33];
  const int tx = threadIdx.x, ty = threadIdx.y;
  const int t0 = blockIdx.x * 32, d0 = blockIdx.y * 32;
  const int bh = blockIdx.z;  // b*16+h
  const int b = bh >> 4, h = bh & 15;
#pragma unroll
  for (int i = 0; i < 4; ++i)
    tile[ty + 8 * i][tx] =
        qkv[(long)(b * T_SEQ + t0 + ty + 8 * i) * (3 * D_MODEL) + 2 * D_MODEL + h * D_HEAD + d0 + tx];
  __syncthreads();
#pragma unroll
  for (int i = 0; i < 4; ++i)
    vt[((long)bh * D_HEAD + d0 + ty + 8 * i) * T_SEQ + t0 + tx] = tile[tx][ty + 8 * i];
}

// ---------------- Flash attention (causal), swapped-QK^T --------------------
// grid: (NT/2, H, B); block 256 = 4 waves x 16 q-rows.
// Each block handles the balanced q-tile pair {qt, NT-1-qt} (33 kt-iters).
// K and V tiles are LDS-staged (shared by all 4 waves), double-buffered,
// XOR-swizzled (linear LDS dest + pre-swizzled global src + swizzled read).
__global__ __launch_bounds__(256) void attn_kernel(
    const unsigned short* __restrict__ qkv, const unsigned short* __restrict__ vt,
    unsigned short* __restrict__ ctx) {
  __shared__ unsigned short Ks[2][64 * 128];   // [kp 64][d 128], 16KB each buf
  __shared__ unsigned short Vs[2][128 * 64];   // [d 128][t 64], 16KB each buf
  const int h = blockIdx.y, b = blockIdx.z;
  const int tid = threadIdx.x;
  const int w = tid >> 6, lane = tid & 63, g = lane >> 4, c = lane & 15;
  const float scale = 0.08838834764831845f;  // 128^-0.5
  const int srcA = (2 * (g & 1)) * 16 + c;
  const int srcB = srcA + 16;
  const bool hi = (g >> 1) != 0;
  const int bh = b * N_HEADS + h;

  // staging: 1024 16B-slots per tile, 4 per thread; source col pre-swizzled
  const int ssk = (tid & 15) ^ ((tid >> 4) & 7);  // K slot-col (16 per row)
  const int ssv = (tid & 7) ^ ((tid >> 3) & 7);   // V slot-col (8 per row)
  const unsigned short* Kg = qkv + (long)b * T_SEQ * 3 * D_MODEL + D_MODEL + (long)h * D_HEAD;
  const unsigned short* Vg = vt + (long)bh * D_HEAD * T_SEQ;

  auto stage = [&](int kv0, int bufi) {
#pragma unroll
    for (int i = 0; i < 4; ++i) {
      const int rowk = i * 16 + (tid >> 4);
      load_lds16(Kg + (long)(kv0 + rowk) * (3 * D_MODEL) + ssk * 8,
                 &Ks[bufi][(i * 256 + tid) * 8]);
    }
#pragma unroll
    for (int i = 0; i < 4; ++i) {
      const int rowv = i * 32 + (tid >> 3);
      load_lds16(Vg + (long)rowv * T_SEQ + kv0 + ssv * 8,
                 &Vs[bufi][(i * 256 + tid) * 8]);
    }
  };

  const int cs7 = c & 7;

  for (int pass = 0; pass < 2; ++pass) {
    const int qt = pass ? (NT - 1 - blockIdx.x) : blockIdx.x;
    const int q = qt * 64 + w * 16 + c;

    bf16x8 fq[4];
    const long rowQ = (long)(b * T_SEQ + q) * (3 * D_MODEL) + h * D_HEAD;
#pragma unroll
    for (int ks = 0; ks < 4; ++ks)
      fq[ks] = *(const bf16x8*)(qkv + rowQ + ks * 32 + g * 8);

    f32x4 o[8] = {};
    float mrun = -INFINITY, ell = 0.0f;

    stage(0, 0);
    asm volatile("s_waitcnt vmcnt(0)" ::: "memory");
    __syncthreads();
    int buf = 0;

    for (int kt = 0; kt <= qt; ++kt) {
      const int kv0 = kt * 64;
      if (kt < qt) stage(kv0 + 64, buf ^ 1);  // prefetch next tile

      // S^T[64 kp][16 q] = K-tile · Q^T  (K from LDS, swizzled read)
      f32x4 s[4] = {};
#pragma unroll
      for (int fm = 0; fm < 4; ++fm) {
        const unsigned short* kr = &Ks[buf][(fm * 16 + c) * 128];
#pragma unroll
        for (int ks = 0; ks < 4; ++ks) {
          bf16x8 ak = *(const bf16x8*)(kr + ((ks * 4 + g) ^ cs7) * 8);
          s[fm] = __builtin_amdgcn_mfma_f32_16x16x32_bf16(ak, fq[ks], s[fm], 0, 0, 0);
        }
      }
      // scale + causal mask + online softmax stats
      float pmax = -INFINITY;
      const bool diag = (kt == qt);
#pragma unroll
      for (int fm = 0; fm < 4; ++fm)
#pragma unroll
        for (int r = 0; r < 4; ++r) {
          float sv = s[fm][r] * scale;
          if (diag) {
            const int kp = kv0 + fm * 16 + 4 * g + r;
            if (kp > q) sv = -INFINITY;
          }
          s[fm][r] = sv;
          pmax = fmaxf(pmax, sv);
        }
      pmax = fmaxf(pmax, __shfl_xor(pmax, 16));
      pmax = fmaxf(pmax, __shfl_xor(pmax, 32));
      const float mnew = fmaxf(mrun, pmax);
      const float resc = __expf(mrun - mnew);
      mrun = mnew;
      float rowsum = 0.0f;
#pragma unroll
      for (int fm = 0; fm < 4; ++fm)
#pragma unroll
        for (int r = 0; r < 4; ++r) {
          const float p = __expf(s[fm][r] - mnew);
          s[fm][r] = p;
          rowsum += p;
        }
      rowsum += __shfl_xor(rowsum, 16);
      rowsum += __shfl_xor(rowsum, 32);
      ell = ell * resc + rowsum;
#pragma unroll
      for (int fm = 0; fm < 8; ++fm) o[fm] *= resc;

      // Redistribute P (S^T layout) -> P^T B-fragments via shuffles
      bf16x8 pb[2];
#pragma unroll
      for (int k2 = 0; k2 < 2; ++k2) {
        float va[4], vb[4];
#pragma unroll
        for (int r = 0; r < 4; ++r) {
          const float t0 = __shfl(s[k2 * 2][r], srcA);
          const float t1 = __shfl(s[k2 * 2 + 1][r], srcA);
          va[r] = hi ? t1 : t0;
          const float u0 = __shfl(s[k2 * 2][r], srcB);
          const float u1 = __shfl(s[k2 * 2 + 1][r], srcB);
          vb[r] = hi ? u1 : u0;
        }
        bf16x8 pv;
        pv[0] = (__bf16)va[0]; pv[1] = (__bf16)va[1];
        pv[2] = (__bf16)va[2]; pv[3] = (__bf16)va[3];
        pv[4] = (__bf16)vb[0]; pv[5] = (__bf16)vb[1];
        pv[6] = (__bf16)vb[2]; pv[7] = (__bf16)vb[3];
        pb[k2] = pv;
      }
      // O^T[128 d][16 q] += V^T · P^T  (V from LDS, swizzled read)
#pragma unroll
      for (int fm = 0; fm < 8; ++fm) {
        const unsigned short* vr = &Vs[buf][(fm * 16 + c) * 64];
#pragma unroll
        for (int k2 = 0; k2 < 2; ++k2) {
          bf16x8 av = *(const bf16x8*)(vr + ((k2 * 4 + g) ^ cs7) * 8);
          o[fm] = __builtin_amdgcn_mfma_f32_16x16x32_bf16(av, pb[k2], o[fm], 0, 0, 0);
        }
      }
      asm volatile("s_waitcnt vmcnt(0)" ::: "memory");
      __syncthreads();
      buf ^= 1;
    }

    const float inv = 1.0f / ell;
    unsigned short* outp = ctx + (long)(b * T_SEQ + q) * D_MODEL + h * D_HEAD;
#pragma unroll
    for (int fm = 0; fm < 8; ++fm) {
      ushort4 pk;
      pk.x = f2bf(o[fm][0] * inv);
      pk.y = f2bf(o[fm][1] * inv);
      pk.z = f2bf(o[fm][2] * inv);
      pk.w = f2bf(o[fm][3] * inv);
      *(ushort4*)(outp + fm * 16 + 4 * g) = pk;
    }
  }
}

// ---------------------------------------------------------------------------
// Workspace budget (~236 MB total, aliased):
//   Wreg  100.7 MB : phase A = wTqkv(25.2)+wTout(8.4); phase B = wTg+wTu+wTo
//   AR     83.9 MB : phase A = qkvb(50.3)+vtb(16.8)+ctxb(16.8);
//                    phase B = gbuf(33.6)+ubuf(33.6)   (N-halved MLP, M=4096)
//   x1     33.6 MB   (fp32 residual stream after attention)
//   hb     16.8 MB   (rmsnorm output, reused)
//   tables  1.0 MB
extern "C" void kernel_launch(void* const* d_in, const int* in_sizes, int n_in,
                              void* d_out, int out_size, void* d_ws, size_t ws_size,
                              hipStream_t stream) {
  const float* x = (const float*)d_in[0];
  const float* w_qkv = (const float*)d_in[1];
  const float* w_out = (const float*)d_in[2];
  const float* g1 = (const float*)d_in[3];
  const float* g2 = (const float*)d_in[4];
  const float* w_g = (const float*)d_in[5];
  const float* w_u = (const float*)d_in[6];
  const float* w_o = (const float*)d_in[7];
  float* out = (float*)d_out;

  char* ws = (char*)d_ws;
  size_t off = 0;
  auto take = [&](size_t bytes) {
    char* p = ws + off;
    off += (bytes + 255) & ~(size_t)255;
    return p;
  };

  // weight region (phase A and phase B alias the same memory)
  char* Wreg = take((size_t)3 * D_FF * D_MODEL * 2);  // 100.66 MB
  unsigned short* wTqkv = (unsigned short*)Wreg;                                   // 25.2 MB
  unsigned short* wTout = (unsigned short*)(Wreg + (size_t)3 * D_MODEL * D_MODEL * 2);  // 8.4 MB
  unsigned short* wTg = (unsigned short*)Wreg;
  unsigned short* wTu = (unsigned short*)(Wreg + (size_t)D_FF * D_MODEL * 2);
  unsigned short* wTo = (unsigned short*)(Wreg + (size_t)2 * D_FF * D_MODEL * 2);

  // activation region (phase A and phase B alias the same memory)
  const size_t qkv_b = (size_t)BT * 3 * D_MODEL * 2;                      // 50.3 MB
  const size_t vt_b = (size_t)B_SZ * N_HEADS * D_HEAD * T_SEQ * 2;        // 16.8 MB
  const size_t ctx_b = (size_t)BT * D_MODEL * 2;                          // 16.8 MB
  char* AR = take(qkv_b + vt_b + ctx_b);                                  // 83.9 MB
  unsigned short* qkvb = (unsigned short*)AR;
  unsigned short* vtb = (unsigned short*)(AR + qkv_b);
  unsigned short* ctxb = (unsigned short*)(AR + qkv_b + vt_b);
  unsigned short* gbuf = (unsigned short*)AR;                                        // 33.6 MB
  unsigned short* ubuf = (unsigned short*)(AR + (size_t)BT * (D_FF / 2) * 2);        // 33.6 MB

  float* x1 = (float*)take((size_t)BT * D_MODEL * 4);
  unsigned short* hb = (unsigned short*)take((size_t)BT * D_MODEL * 2);
  float* cost = (float*)take((size_t)T_SEQ * 64 * 4);
  float* sint = (float*)take((size_t)T_SEQ * 64 * 4);

  const dim3 tb(32, 8);

  // ---- phase A: attention ----
  transpose_cast_kernel<<<dim3(3 * D_MODEL / 32, D_MODEL / 32), tb, 0, stream>>>(w_qkv, wTqkv, D_MODEL, 3 * D_MODEL);
  transpose_cast_kernel<<<dim3(D_MODEL / 32, D_MODEL / 32), tb, 0, stream>>>(w_out, wTout, D_MODEL, D_MODEL);
  rope_tables_kernel<<<T_SEQ * 64 / 256, 256, 0, stream>>>(cost, sint);

  rmsnorm_cast_kernel<<<BT, 256, 0, stream>>>(x, g1, hb);
  gemm_bt_kernel<0><<<dim3(3 * D_MODEL / 128, BT / 128), 256, 0, stream>>>(
      hb, wTqkv, qkvb, nullptr, BT, 3 * D_MODEL, D_MODEL, D_MODEL, D_MODEL, 3 * D_MODEL);
  rope_apply_kernel<<<(BT * N_HEADS * 64 * 2) / 256, 256, 0, stream>>>(qkvb, cost, sint);
  vtrans_kernel<<<dim3(T_SEQ / 32, D_HEAD / 32, B_SZ * N_HEADS), tb, 0, stream>>>(qkvb, vtb);
  attn_kernel<<<dim3(NT / 2, N_HEADS, B_SZ), 256, 0, stream>>>(qkvb, vtb, ctxb);
  gemm_bt_kernel<1><<<dim3(D_MODEL / 128, BT / 128), 256, 0, stream>>>(
      ctxb, wTout, x1, x, BT, D_MODEL, D_MODEL, D_MODEL, D_MODEL, D_MODEL);

  // ---- phase B: MLP, N-halved (M=4096 everywhere) ----
  transpose_cast_kernel<<<dim3(D_FF / 32, D_MODEL / 32), tb, 0, stream>>>(w_g, wTg, D_MODEL, D_FF);
  transpose_cast_kernel<<<dim3(D_FF / 32, D_MODEL / 32), tb, 0, stream>>>(w_u, wTu, D_MODEL, D_FF);
  transpose_cast_kernel<<<dim3(D_MODEL / 32, D_FF / 32), tb, 0, stream>>>(w_o, wTo, D_FF, D_MODEL);
  rmsnorm_cast_kernel<<<BT, 256, 0, stream>>>(x1, g2, hb);

  const int NH = D_FF / 2;  // 4096 ff-columns per half
  for (int half = 0; half < 2; ++half) {
    const unsigned short* wTu_h = wTu + (size_t)half * NH * D_MODEL;
    const unsigned short* wTg_h = wTg + (size_t)half * NH * D_MODEL;
    const unsigned short* wTo_h = wTo + (size_t)half * NH;  // K-slice of [2048][8192]
    // up half -> ubuf
    gemm_bt_kernel<0><<<dim3(NH / 128, BT / 128), 256, 0, stream>>>(
        hb, wTu_h, ubuf, nullptr, BT, NH, D_MODEL, D_MODEL, D_MODEL, NH);
    // gate half, fused SwiGLU epilogue (reads ubuf) -> gbuf
    gemm_bt_kernel<2><<<dim3(NH / 128, BT / 128), 256, 0, stream>>>(
        hb, wTg_h, gbuf, ubuf, BT, NH, D_MODEL, D_MODEL, D_MODEL, NH);
    // down half: out = gbuf @ wTo[:, half] + (half==0 ? x1 : out)
    gemm_bt_kernel<1><<<dim3(D_MODEL / 128, BT / 128), 256, 0, stream>>>(
        gbuf, wTo_h, out, (half == 0) ? x1 : out, BT, D_MODEL, NH, NH, D_FF, D_MODEL);
  }
}

// Round 5
// 913.679 us; speedup vs baseline: 1.7832x; 1.1471x over previous
//
#include <hip/hip_runtime.h>

typedef __bf16 bf16x8 __attribute__((ext_vector_type(8)));
typedef float f32x4 __attribute__((ext_vector_type(4)));
typedef unsigned short u16x8 __attribute__((ext_vector_type(8)));

#define B_SZ 2
#define T_SEQ 2048
#define D_MODEL 2048
#define N_HEADS 16
#define D_HEAD 128
#define D_FF 8192
#define BT (B_SZ * T_SEQ)
#define NT (T_SEQ / 64)

__device__ __forceinline__ unsigned short f2bf(float f) {
  unsigned int u = __builtin_bit_cast(unsigned int, f);
  u += 0x7FFFu + ((u >> 16) & 1u);
  return (unsigned short)(u >> 16);
}
__device__ __forceinline__ float bf2f(unsigned short h) {
  unsigned int u = ((unsigned int)h) << 16;
  return __builtin_bit_cast(float, u);
}

__device__ __forceinline__ void load_lds16(const void* g, void* l) {
  __builtin_amdgcn_global_load_lds(
      (const __attribute__((address_space(1))) unsigned int*)g,
      (__attribute__((address_space(3))) unsigned int*)l, 16, 0, 0);
}

// ---------------- transpose + cast: in fp32 [R][C] -> out bf16 [C][R] -------
__global__ __launch_bounds__(256) void transpose_cast_kernel(
    const float* __restrict__ in, unsigned short* __restrict__ out, int R, int C) {
  __shared__ float tile[32][33];
  const int tx = threadIdx.x, ty = threadIdx.y;
  const int c0 = blockIdx.x * 32, r0 = blockIdx.y * 32;
#pragma unroll
  for (int i = 0; i < 4; ++i)
    tile[ty + 8 * i][tx] = in[(long)(r0 + ty + 8 * i) * C + c0 + tx];
  __syncthreads();
#pragma unroll
  for (int i = 0; i < 4; ++i)
    out[(long)(c0 + ty + 8 * i) * R + r0 + tx] = f2bf(tile[tx][ty + 8 * i]);
}

// ---------------- RMSNorm fp32 row -> bf16 ----------------------------------
__global__ __launch_bounds__(256) void rmsnorm_cast_kernel(
    const float* __restrict__ x, const float* __restrict__ gw,
    unsigned short* __restrict__ out) {
  const int row = blockIdx.x;
  const int tid = threadIdx.x;
  const float* xr = x + (long)row * D_MODEL;
  float4 a = *(const float4*)(xr + tid * 8);
  float4 b = *(const float4*)(xr + tid * 8 + 4);
  float ss = a.x * a.x + a.y * a.y + a.z * a.z + a.w * a.w +
             b.x * b.x + b.y * b.y + b.z * b.z + b.w * b.w;
#pragma unroll
  for (int d = 1; d < 64; d <<= 1) ss += __shfl_xor(ss, d);
  __shared__ float part[4];
  if ((tid & 63) == 0) part[tid >> 6] = ss;
  __syncthreads();
  ss = part[0] + part[1] + part[2] + part[3];
  const float rs = rsqrtf(ss * (1.0f / D_MODEL) + 1e-6f);
  float4 g0 = *(const float4*)(gw + tid * 8);
  float4 g1 = *(const float4*)(gw + tid * 8 + 4);
  ushort4 o0, o1;
  o0.x = f2bf(a.x * rs * g0.x); o0.y = f2bf(a.y * rs * g0.y);
  o0.z = f2bf(a.z * rs * g0.z); o0.w = f2bf(a.w * rs * g0.w);
  o1.x = f2bf(b.x * rs * g1.x); o1.y = f2bf(b.y * rs * g1.y);
  o1.z = f2bf(b.z * rs * g1.z); o1.w = f2bf(b.w * rs * g1.w);
  unsigned short* op = out + (long)row * D_MODEL + tid * 8;
  *(ushort4*)op = o0;
  *(ushort4*)(op + 4) = o1;
}

// ---------------- 128x128 m97-style GEMM (kept for N=2048 outputs) ----------
// EPI: 0 = bf16 store; 1 = fp32 store + fp32 resid add; 2 = silu(acc)*aux(bf16)
template <int EPI>
__global__ __launch_bounds__(256) void gemm_bt_kernel(
    const unsigned short* __restrict__ A, const unsigned short* __restrict__ Bt,
    void* __restrict__ Cout, const void* __restrict__ aux,
    int M, int N, int K, int lda, int ldb, int ldc) {
  __shared__ unsigned short As[128 * 32];
  __shared__ unsigned short Bs[128 * 32];
  const int tid = threadIdx.x;
  const int w = tid >> 6, lane = tid & 63, g = lane >> 4, c = lane & 15;
  const int m0 = blockIdx.y * 128, n0 = blockIdx.x * 128;
  const int wm = (w >> 1) * 64, wn = (w & 1) * 64;
  const int srow = lane >> 2;
  const int scol = (lane & 3) * 8;
  const int ch0 = w * 2;
  f32x4 acc[4][4] = {};
  const int nkt = K >> 5;
  const unsigned short* Abase = A + (long)m0 * lda + scol;
  const unsigned short* Bbase = Bt + (long)n0 * ldb + scol;
  for (int kt = 0; kt < nkt; ++kt) {
    __syncthreads();
#pragma unroll
    for (int i = 0; i < 2; ++i) {
      const int ch = ch0 + i;
      load_lds16(Abase + (long)(ch * 16 + srow) * lda + kt * 32, &As[ch * 512]);
      load_lds16(Bbase + (long)(ch * 16 + srow) * ldb + kt * 32, &Bs[ch * 512]);
    }
    __syncthreads();
    bf16x8 fa[4], fb[4];
#pragma unroll
    for (int m = 0; m < 4; ++m)
      fa[m] = *(const bf16x8*)(As + (wm + m * 16 + c) * 32 + g * 8);
#pragma unroll
    for (int n = 0; n < 4; ++n)
      fb[n] = *(const bf16x8*)(Bs + (wn + n * 16 + c) * 32 + g * 8);
#pragma unroll
    for (int m = 0; m < 4; ++m)
#pragma unroll
      for (int n = 0; n < 4; ++n)
        acc[m][n] = __builtin_amdgcn_mfma_f32_16x16x32_bf16(fa[m], fb[n], acc[m][n], 0, 0, 0);
  }
#pragma unroll
  for (int m = 0; m < 4; ++m) {
#pragma unroll
    for (int r = 0; r < 4; ++r) {
      const int row = m0 + wm + m * 16 + 4 * g + r;
#pragma unroll
      for (int n = 0; n < 4; ++n) {
        const int col = n0 + wn + n * 16 + c;
        const long idx = (long)row * ldc + col;
        float v = acc[m][n][r];
        if constexpr (EPI == 0) {
          ((unsigned short*)Cout)[idx] = f2bf(v);
        } else if constexpr (EPI == 1) {
          ((float*)Cout)[idx] = v + ((const float*)aux)[idx];
        } else {
          const float u = bf2f(((const unsigned short*)aux)[idx]);
          const float s = v / (1.0f + __expf(-v));
          ((unsigned short*)Cout)[idx] = f2bf(s * u);
        }
      }
    }
  }
}

// ---------------- 256x256 counted-vmcnt GEMM (T3/T4 + T2 swizzle) -----------
// 512 threads = 8 waves (2 M x 4 N), per-wave 128x64 output. BK=64.
// LDS: 2 buffers x (A 256x64 + B 256x64) bf16 = 128 KiB, tile double-buffer.
// Stage tile kt+2 after the read-barrier; s_waitcnt vmcnt(8) (never 0 in
// steady state) so tile kt+1's 8 loads/thread stay in flight across compute.
// LDS XOR swizzle: slot^(row&7), pre-swizzled global src + swizzled ds_read.
template <int EPI>
__global__ __launch_bounds__(512, 2) void gemm256_kernel(
    const unsigned short* __restrict__ A, const unsigned short* __restrict__ Bt,
    void* __restrict__ Cout, const void* __restrict__ aux,
    int M, int N, int K, int lda, int ldb, int ldc) {
  __shared__ unsigned short As[2][16384];  // [buf][half(128rows) x 64k]
  __shared__ unsigned short Bs[2][16384];
  const int tid = threadIdx.x;
  const int lane = tid & 63, g = lane >> 4, c = lane & 15;
  const int w = tid >> 6, wr = w >> 2, wc = w & 3;

  // XCD-aware bijective swizzle (requires nwg % 8 == 0; true for all our uses)
  const int nbn = N >> 8;
  const int nwg = (M >> 8) * nbn;
  const int bid = (int)blockIdx.x;
  const int swz = (bid & 7) * (nwg >> 3) + (bid >> 3);
  const int m0 = (swz / nbn) << 8, n0 = (swz % nbn) << 8;

  const int nkt = K >> 6;
  // staging: 2 16B-slots per thread per half-panel (1024 slots each)
  const int L0 = tid, L1 = 512 + tid;
  const int row0 = L0 >> 3, cs0 = ((L0 & 7) ^ (row0 & 7)) * 8;
  const int row1 = L1 >> 3, cs1 = ((L1 & 7) ^ (row1 & 7)) * 8;
  const int wbase = (tid & ~63) * 8;  // wave-uniform LDS elem base (lane*16B implied)
  const unsigned short* Abase = A + (long)m0 * lda;
  const unsigned short* Bbase = Bt + (long)n0 * ldb;

  auto stage = [&](int kt, int bufi) {
    const long kofs = (long)kt * 64;
#pragma unroll
    for (int h = 0; h < 2; ++h) {
      load_lds16(Abase + (long)(h * 128 + row0) * lda + kofs + cs0,
                 &As[bufi][h * 8192 + wbase]);
      load_lds16(Abase + (long)(h * 128 + row1) * lda + kofs + cs1,
                 &As[bufi][h * 8192 + 4096 + wbase]);
    }
#pragma unroll
    for (int h = 0; h < 2; ++h) {
      load_lds16(Bbase + (long)(h * 128 + row0) * ldb + kofs + cs0,
                 &Bs[bufi][h * 8192 + wbase]);
      load_lds16(Bbase + (long)(h * 128 + row1) * ldb + kofs + cs1,
                 &Bs[bufi][h * 8192 + 4096 + wbase]);
    }
  };

  f32x4 acc[8][4] = {};
  const int c7 = c & 7;

  stage(0, 0);
  if (nkt > 1) stage(1, 1);
  asm volatile("s_waitcnt vmcnt(8)" ::: "memory");
  __builtin_amdgcn_sched_barrier(0);
  __builtin_amdgcn_s_barrier();

  for (int kt = 0; kt < nkt; ++kt) {
    const int bufi = kt & 1;
    const unsigned short* Ap = &As[bufi][wr * 8192];
    const unsigned short* Bp = &Bs[bufi][(wc >> 1) * 8192 + (wc & 1) * 4096];
    bf16x8 fb[4][2];
#pragma unroll
    for (int fn = 0; fn < 4; ++fn)
#pragma unroll
      for (int ks = 0; ks < 2; ++ks)
        fb[fn][ks] = *(const bf16x8*)(Bp + (fn * 16 + c) * 64 + (((ks * 4 + g) ^ c7) * 8));
#pragma unroll
    for (int fm = 0; fm < 8; ++fm) {
      const unsigned short* ar = Ap + (fm * 16 + c) * 64;
      bf16x8 fa0 = *(const bf16x8*)(ar + ((g ^ c7) * 8));
      bf16x8 fa1 = *(const bf16x8*)(ar + (((4 + g) ^ c7) * 8));
#pragma unroll
      for (int fn = 0; fn < 4; ++fn) {
        acc[fm][fn] = __builtin_amdgcn_mfma_f32_16x16x32_bf16(fa0, fb[fn][0], acc[fm][fn], 0, 0, 0);
        acc[fm][fn] = __builtin_amdgcn_mfma_f32_16x16x32_bf16(fa1, fb[fn][1], acc[fm][fn], 0, 0, 0);
      }
    }
    if (kt + 1 == nkt) break;
    // all my ds_reads serviced before anyone overwrites this buffer
    asm volatile("s_waitcnt lgkmcnt(0)" ::: "memory");
    __builtin_amdgcn_sched_barrier(0);
    __builtin_amdgcn_s_barrier();
    if (kt + 2 < nkt) {
      stage(kt + 2, bufi);
      asm volatile("s_waitcnt vmcnt(8)" ::: "memory");
    } else {
      asm volatile("s_waitcnt vmcnt(0)" ::: "memory");
    }
    __builtin_amdgcn_sched_barrier(0);
    __builtin_amdgcn_s_barrier();
  }

#pragma unroll
  for (int fm = 0; fm < 8; ++fm) {
#pragma unroll
    for (int r = 0; r < 4; ++r) {
      const int row = m0 + wr * 128 + fm * 16 + 4 * g + r;
#pragma unroll
      for (int fn = 0; fn < 4; ++fn) {
        const int col = n0 + wc * 64 + fn * 16 + c;
        const long idx = (long)row * ldc + col;
        float v = acc[fm][fn][r];
        if constexpr (EPI == 0) {
          ((unsigned short*)Cout)[idx] = f2bf(v);
        } else if constexpr (EPI == 1) {
          ((float*)Cout)[idx] = v + ((const float*)aux)[idx];
        } else {
          const float u = bf2f(((const unsigned short*)aux)[idx]);
          const float s = v / (1.0f + __expf(-v));
          ((unsigned short*)Cout)[idx] = f2bf(s * u);
        }
      }
    }
  }
}

// ---------------- RoPE tables -----------------------------------------------
__global__ void rope_tables_kernel(float* __restrict__ cost, float* __restrict__ sint) {
  const int idx = blockIdx.x * 256 + threadIdx.x;  // T*64
  const int t = idx >> 6, i = idx & 63;
  const float invf = powf(10000.0f, -(float)i * (1.0f / 64.0f));
  const float ang = (float)t * invf;
  cost[idx] = cosf(ang);
  sint[idx] = sinf(ang);
}

// ---------------- RoPE apply in-place on q,k halves of qkv(bf16) ------------
__global__ __launch_bounds__(256) void rope_apply_kernel(
    unsigned short* __restrict__ qkv, const float* __restrict__ cost,
    const float* __restrict__ sint) {
  const long idx = (long)blockIdx.x * 256 + threadIdx.x;  // BT*16*64*2
  const int i = idx & 63;
  const int h = (idx >> 6) & 15;
  const int qk = (idx >> 10) & 1;
  const int row = idx >> 11;          // 0..BT-1
  const int t = row & (T_SEQ - 1);
  unsigned short* p = qkv + (long)row * (3 * D_MODEL) + qk * D_MODEL + h * D_HEAD + i;
  const float a = bf2f(p[0]);
  const float b = bf2f(p[64]);
  const float cv = cost[t * 64 + i];
  const float sv = sint[t * 64 + i];
  p[0] = f2bf(a * cv - b * sv);
  p[64] = f2bf(b * cv + a * sv);
}

// ---------------- V transpose: qkv v-part -> vt [B,H,128,T] bf16 ------------
__global__ __launch_bounds__(256) void vtrans_kernel(
    const unsigned short* __restrict__ qkv, unsigned short* __restrict__ vt) {
  __shared__ unsigned short tile[32][33];
  const int tx = threadIdx.x, ty = threadIdx.y;
  const int t0 = blockIdx.x * 32, d0 = blockIdx.y * 32;
  const int bh = blockIdx.z;  // b*16+h
  const int b = bh >> 4, h = bh & 15;
#pragma unroll
  for (int i = 0; i < 4; ++i)
    tile[ty + 8 * i][tx] =
        qkv[(long)(b * T_SEQ + t0 + ty + 8 * i) * (3 * D_MODEL) + 2 * D_MODEL + h * D_HEAD + d0 + tx];
  __syncthreads();
#pragma unroll
  for (int i = 0; i < 4; ++i)
    vt[((long)bh * D_HEAD + d0 + ty + 8 * i) * T_SEQ + t0 + tx] = tile[tx][ty + 8 * i];
}

// ---------------- Flash attention (causal), swapped-QK^T --------------------
__global__ __launch_bounds__(256) void attn_kernel(
    const unsigned short* __restrict__ qkv, const unsigned short* __restrict__ vt,
    unsigned short* __restrict__ ctx) {
  __shared__ unsigned short Ks[2][64 * 128];
  __shared__ unsigned short Vs[2][128 * 64];
  const int h = blockIdx.y, b = blockIdx.z;
  const int tid = threadIdx.x;
  const int w = tid >> 6, lane = tid & 63, g = lane >> 4, c = lane & 15;
  const float scale = 0.08838834764831845f;  // 128^-0.5
  const int srcA = (2 * (g & 1)) * 16 + c;
  const int srcB = srcA + 16;
  const bool hi = (g >> 1) != 0;
  const int bh = b * N_HEADS + h;

  const int ssk = (tid & 15) ^ ((tid >> 4) & 7);
  const int ssv = (tid & 7) ^ ((tid >> 3) & 7);
  const unsigned short* Kg = qkv + (long)b * T_SEQ * 3 * D_MODEL + D_MODEL + (long)h * D_HEAD;
  const unsigned short* Vg = vt + (long)bh * D_HEAD * T_SEQ;

  auto stage = [&](int kv0, int bufi) {
#pragma unroll
    for (int i = 0; i < 4; ++i) {
      const int rowk = i * 16 + (tid >> 4);
      load_lds16(Kg + (long)(kv0 + rowk) * (3 * D_MODEL) + ssk * 8,
                 &Ks[bufi][(i * 256 + tid) * 8]);
    }
#pragma unroll
    for (int i = 0; i < 4; ++i) {
      const int rowv = i * 32 + (tid >> 3);
      load_lds16(Vg + (long)rowv * T_SEQ + kv0 + ssv * 8,
                 &Vs[bufi][(i * 256 + tid) * 8]);
    }
  };

  const int cs7 = c & 7;

  for (int pass = 0; pass < 2; ++pass) {
    const int qt = pass ? (NT - 1 - blockIdx.x) : blockIdx.x;
    const int q = qt * 64 + w * 16 + c;

    bf16x8 fq[4];
    const long rowQ = (long)(b * T_SEQ + q) * (3 * D_MODEL) + h * D_HEAD;
#pragma unroll
    for (int ks = 0; ks < 4; ++ks)
      fq[ks] = *(const bf16x8*)(qkv + rowQ + ks * 32 + g * 8);

    f32x4 o[8] = {};
    float mrun = -INFINITY, ell = 0.0f;

    stage(0, 0);
    asm volatile("s_waitcnt vmcnt(0)" ::: "memory");
    __syncthreads();
    int buf = 0;

    for (int kt = 0; kt <= qt; ++kt) {
      const int kv0 = kt * 64;
      if (kt < qt) stage(kv0 + 64, buf ^ 1);

      f32x4 s[4] = {};
#pragma unroll
      for (int fm = 0; fm < 4; ++fm) {
        const unsigned short* kr = &Ks[buf][(fm * 16 + c) * 128];
#pragma unroll
        for (int ks = 0; ks < 4; ++ks) {
          bf16x8 ak = *(const bf16x8*)(kr + ((ks * 4 + g) ^ cs7) * 8);
          s[fm] = __builtin_amdgcn_mfma_f32_16x16x32_bf16(ak, fq[ks], s[fm], 0, 0, 0);
        }
      }
      float pmax = -INFINITY;
      const bool diag = (kt == qt);
#pragma unroll
      for (int fm = 0; fm < 4; ++fm)
#pragma unroll
        for (int r = 0; r < 4; ++r) {
          float sv = s[fm][r] * scale;
          if (diag) {
            const int kp = kv0 + fm * 16 + 4 * g + r;
            if (kp > q) sv = -INFINITY;
          }
          s[fm][r] = sv;
          pmax = fmaxf(pmax, sv);
        }
      pmax = fmaxf(pmax, __shfl_xor(pmax, 16));
      pmax = fmaxf(pmax, __shfl_xor(pmax, 32));
      const float mnew = fmaxf(mrun, pmax);
      const float resc = __expf(mrun - mnew);
      mrun = mnew;
      float rowsum = 0.0f;
#pragma unroll
      for (int fm = 0; fm < 4; ++fm)
#pragma unroll
        for (int r = 0; r < 4; ++r) {
          const float p = __expf(s[fm][r] - mnew);
          s[fm][r] = p;
          rowsum += p;
        }
      rowsum += __shfl_xor(rowsum, 16);
      rowsum += __shfl_xor(rowsum, 32);
      ell = ell * resc + rowsum;
#pragma unroll
      for (int fm = 0; fm < 8; ++fm) o[fm] *= resc;

      bf16x8 pb[2];
#pragma unroll
      for (int k2 = 0; k2 < 2; ++k2) {
        float va[4], vb[4];
#pragma unroll
        for (int r = 0; r < 4; ++r) {
          const float t0 = __shfl(s[k2 * 2][r], srcA);
          const float t1 = __shfl(s[k2 * 2 + 1][r], srcA);
          va[r] = hi ? t1 : t0;
          const float u0 = __shfl(s[k2 * 2][r], srcB);
          const float u1 = __shfl(s[k2 * 2 + 1][r], srcB);
          vb[r] = hi ? u1 : u0;
        }
        bf16x8 pv;
        pv[0] = (__bf16)va[0]; pv[1] = (__bf16)va[1];
        pv[2] = (__bf16)va[2]; pv[3] = (__bf16)va[3];
        pv[4] = (__bf16)vb[0]; pv[5] = (__bf16)vb[1];
        pv[6] = (__bf16)vb[2]; pv[7] = (__bf16)vb[3];
        pb[k2] = pv;
      }
#pragma unroll
      for (int fm = 0; fm < 8; ++fm) {
        const unsigned short* vr = &Vs[buf][(fm * 16 + c) * 64];
#pragma unroll
        for (int k2 = 0; k2 < 2; ++k2) {
          bf16x8 av = *(const bf16x8*)(vr + ((k2 * 4 + g) ^ cs7) * 8);
          o[fm] = __builtin_amdgcn_mfma_f32_16x16x32_bf16(av, pb[k2], o[fm], 0, 0, 0);
        }
      }
      asm volatile("s_waitcnt vmcnt(0)" ::: "memory");
      __syncthreads();
      buf ^= 1;
    }

    const float inv = 1.0f / ell;
    unsigned short* outp = ctx + (long)(b * T_SEQ + q) * D_MODEL + h * D_HEAD;
#pragma unroll
    for (int fm = 0; fm < 8; ++fm) {
      ushort4 pk;
      pk.x = f2bf(o[fm][0] * inv);
      pk.y = f2bf(o[fm][1] * inv);
      pk.z = f2bf(o[fm][2] * inv);
      pk.w = f2bf(o[fm][3] * inv);
      *(ushort4*)(outp + fm * 16 + 4 * g) = pk;
    }
  }
}

// ---------------------------------------------------------------------------
extern "C" void kernel_launch(void* const* d_in, const int* in_sizes, int n_in,
                              void* d_out, int out_size, void* d_ws, size_t ws_size,
                              hipStream_t stream) {
  const float* x = (const float*)d_in[0];
  const float* w_qkv = (const float*)d_in[1];
  const float* w_out = (const float*)d_in[2];
  const float* g1 = (const float*)d_in[3];
  const float* g2 = (const float*)d_in[4];
  const float* w_g = (const float*)d_in[5];
  const float* w_u = (const float*)d_in[6];
  const float* w_o = (const float*)d_in[7];
  float* out = (float*)d_out;

  char* ws = (char*)d_ws;
  size_t off = 0;
  auto take = [&](size_t bytes) {
    char* p = ws + off;
    off += (bytes + 255) & ~(size_t)255;
    return p;
  };

  // weight region (phase A and phase B alias the same memory)
  char* Wreg = take((size_t)3 * D_FF * D_MODEL * 2);  // 100.66 MB
  unsigned short* wTqkv = (unsigned short*)Wreg;
  unsigned short* wTout = (unsigned short*)(Wreg + (size_t)3 * D_MODEL * D_MODEL * 2);
  unsigned short* wTg = (unsigned short*)Wreg;
  unsigned short* wTu = (unsigned short*)(Wreg + (size_t)D_FF * D_MODEL * 2);
  unsigned short* wTo = (unsigned short*)(Wreg + (size_t)2 * D_FF * D_MODEL * 2);

  // activation region (phase A and phase B alias the same memory)
  const size_t qkv_b = (size_t)BT * 3 * D_MODEL * 2;
  const size_t vt_b = (size_t)B_SZ * N_HEADS * D_HEAD * T_SEQ * 2;
  const size_t ctx_b = (size_t)BT * D_MODEL * 2;
  char* AR = take(qkv_b + vt_b + ctx_b);  // 83.9 MB
  unsigned short* qkvb = (unsigned short*)AR;
  unsigned short* vtb = (unsigned short*)(AR + qkv_b);
  unsigned short* ctxb = (unsigned short*)(AR + qkv_b + vt_b);
  unsigned short* gbuf = (unsigned short*)AR;                                  // 33.6 MB
  unsigned short* ubuf = (unsigned short*)(AR + (size_t)BT * (D_FF / 2) * 2);  // 33.6 MB

  float* x1 = (float*)take((size_t)BT * D_MODEL * 4);
  unsigned short* hb = (unsigned short*)take((size_t)BT * D_MODEL * 2);
  float* cost = (float*)take((size_t)T_SEQ * 64 * 4);
  float* sint = (float*)take((size_t)T_SEQ * 64 * 4);

  const dim3 tb(32, 8);

  // ---- phase A: attention ----
  transpose_cast_kernel<<<dim3(3 * D_MODEL / 32, D_MODEL / 32), tb, 0, stream>>>(w_qkv, wTqkv, D_MODEL, 3 * D_MODEL);
  transpose_cast_kernel<<<dim3(D_MODEL / 32, D_MODEL / 32), tb, 0, stream>>>(w_out, wTout, D_MODEL, D_MODEL);
  rope_tables_kernel<<<T_SEQ * 64 / 256, 256, 0, stream>>>(cost, sint);

  rmsnorm_cast_kernel<<<BT, 256, 0, stream>>>(x, g1, hb);
  // QKV: 256^2 counted-vmcnt kernel, grid 16x24 = 384 blocks (1-D, swizzled)
  gemm256_kernel<0><<<(BT / 256) * (3 * D_MODEL / 256), 512, 0, stream>>>(
      hb, wTqkv, qkvb, nullptr, BT, 3 * D_MODEL, D_MODEL, D_MODEL, D_MODEL, 3 * D_MODEL);
  rope_apply_kernel<<<(BT * N_HEADS * 64 * 2) / 256, 256, 0, stream>>>(qkvb, cost, sint);
  vtrans_kernel<<<dim3(T_SEQ / 32, D_HEAD / 32, B_SZ * N_HEADS), tb, 0, stream>>>(qkvb, vtb);
  attn_kernel<<<dim3(NT / 2, N_HEADS, B_SZ), 256, 0, stream>>>(qkvb, vtb, ctxb);
  gemm_bt_kernel<1><<<dim3(D_MODEL / 128, BT / 128), 256, 0, stream>>>(
      ctxb, wTout, x1, x, BT, D_MODEL, D_MODEL, D_MODEL, D_MODEL, D_MODEL);

  // ---- phase B: MLP, N-halved (M=4096 everywhere) ----
  transpose_cast_kernel<<<dim3(D_FF / 32, D_MODEL / 32), tb, 0, stream>>>(w_g, wTg, D_MODEL, D_FF);
  transpose_cast_kernel<<<dim3(D_FF / 32, D_MODEL / 32), tb, 0, stream>>>(w_u, wTu, D_MODEL, D_FF);
  transpose_cast_kernel<<<dim3(D_MODEL / 32, D_FF / 32), tb, 0, stream>>>(w_o, wTo, D_FF, D_MODEL);
  rmsnorm_cast_kernel<<<BT, 256, 0, stream>>>(x1, g2, hb);

  const int NH = D_FF / 2;  // 4096 ff-columns per half
  for (int half = 0; half < 2; ++half) {
    const unsigned short* wTu_h = wTu + (size_t)half * NH * D_MODEL;
    const unsigned short* wTg_h = wTg + (size_t)half * NH * D_MODEL;
    const unsigned short* wTo_h = wTo + (size_t)half * NH;  // K-slice of [2048][8192]
    // up half -> ubuf (256^2 kernel, 16x16 = 256 blocks)
    gemm256_kernel<0><<<(BT / 256) * (NH / 256), 512, 0, stream>>>(
        hb, wTu_h, ubuf, nullptr, BT, NH, D_MODEL, D_MODEL, D_MODEL, NH);
    // gate half, fused SwiGLU epilogue (reads ubuf) -> gbuf
    gemm256_kernel<2><<<(BT / 256) * (NH / 256), 512, 0, stream>>>(
        hb, wTg_h, gbuf, ubuf, BT, NH, D_MODEL, D_MODEL, D_MODEL, NH);
    // down half: out = gbuf @ wTo[:, half] + (half==0 ? x1 : out)  (m97 kernel)
    gemm_bt_kernel<1><<<dim3(D_MODEL / 128, BT / 128), 256, 0, stream>>>(
        gbuf, wTo_h, out, (half == 0) ? x1 : out, BT, D_MODEL, NH, NH, D_FF, D_MODEL);
  }
}

// Round 6
// 804.456 us; speedup vs baseline: 2.0253x; 1.1358x over previous
//
#include <hip/hip_runtime.h>

typedef __bf16 bf16x8 __attribute__((ext_vector_type(8)));
typedef float f32x4 __attribute__((ext_vector_type(4)));
typedef unsigned short u16x8 __attribute__((ext_vector_type(8)));

#define B_SZ 2
#define T_SEQ 2048
#define D_MODEL 2048
#define N_HEADS 16
#define D_HEAD 128
#define D_FF 8192
#define BT (B_SZ * T_SEQ)
#define NT (T_SEQ / 64)

__device__ __forceinline__ unsigned short f2bf(float f) {
  unsigned int u = __builtin_bit_cast(unsigned int, f);
  u += 0x7FFFu + ((u >> 16) & 1u);
  return (unsigned short)(u >> 16);
}
__device__ __forceinline__ float bf2f(unsigned short h) {
  unsigned int u = ((unsigned int)h) << 16;
  return __builtin_bit_cast(float, u);
}

__device__ __forceinline__ void load_lds16(const void* g, void* l) {
  __builtin_amdgcn_global_load_lds(
      (const __attribute__((address_space(1))) unsigned int*)g,
      (__attribute__((address_space(3))) unsigned int*)l, 16, 0, 0);
}

// ---------------- transpose + cast: in fp32 [R][C] -> out bf16 [C][R] -------
__global__ __launch_bounds__(256) void transpose_cast_kernel(
    const float* __restrict__ in, unsigned short* __restrict__ out, int R, int C) {
  __shared__ float tile[32][33];
  const int tx = threadIdx.x, ty = threadIdx.y;
  const int c0 = blockIdx.x * 32, r0 = blockIdx.y * 32;
#pragma unroll
  for (int i = 0; i < 4; ++i)
    tile[ty + 8 * i][tx] = in[(long)(r0 + ty + 8 * i) * C + c0 + tx];
  __syncthreads();
#pragma unroll
  for (int i = 0; i < 4; ++i)
    out[(long)(c0 + ty + 8 * i) * R + r0 + tx] = f2bf(tile[tx][ty + 8 * i]);
}

// ---------------- RMSNorm fp32 row -> bf16 ----------------------------------
__global__ __launch_bounds__(256) void rmsnorm_cast_kernel(
    const float* __restrict__ x, const float* __restrict__ gw,
    unsigned short* __restrict__ out) {
  const int row = blockIdx.x;
  const int tid = threadIdx.x;
  const float* xr = x + (long)row * D_MODEL;
  float4 a = *(const float4*)(xr + tid * 8);
  float4 b = *(const float4*)(xr + tid * 8 + 4);
  float ss = a.x * a.x + a.y * a.y + a.z * a.z + a.w * a.w +
             b.x * b.x + b.y * b.y + b.z * b.z + b.w * b.w;
#pragma unroll
  for (int d = 1; d < 64; d <<= 1) ss += __shfl_xor(ss, d);
  __shared__ float part[4];
  if ((tid & 63) == 0) part[tid >> 6] = ss;
  __syncthreads();
  ss = part[0] + part[1] + part[2] + part[3];
  const float rs = rsqrtf(ss * (1.0f / D_MODEL) + 1e-6f);
  float4 g0 = *(const float4*)(gw + tid * 8);
  float4 g1 = *(const float4*)(gw + tid * 8 + 4);
  ushort4 o0, o1;
  o0.x = f2bf(a.x * rs * g0.x); o0.y = f2bf(a.y * rs * g0.y);
  o0.z = f2bf(a.z * rs * g0.z); o0.w = f2bf(a.w * rs * g0.w);
  o1.x = f2bf(b.x * rs * g1.x); o1.y = f2bf(b.y * rs * g1.y);
  o1.z = f2bf(b.z * rs * g1.z); o1.w = f2bf(b.w * rs * g1.w);
  unsigned short* op = out + (long)row * D_MODEL + tid * 8;
  *(ushort4*)op = o0;
  *(ushort4*)(op + 4) = o1;
}

// ---------------- 128x128 m97-style GEMM (fallback, currently unused) -------
template <int EPI>
__global__ __launch_bounds__(256) void gemm_bt_kernel(
    const unsigned short* __restrict__ A, const unsigned short* __restrict__ Bt,
    void* __restrict__ Cout, const void* __restrict__ aux,
    int M, int N, int K, int lda, int ldb, int ldc) {
  __shared__ unsigned short As[128 * 32];
  __shared__ unsigned short Bs[128 * 32];
  const int tid = threadIdx.x;
  const int w = tid >> 6, lane = tid & 63, g = lane >> 4, c = lane & 15;
  const int m0 = blockIdx.y * 128, n0 = blockIdx.x * 128;
  const int wm = (w >> 1) * 64, wn = (w & 1) * 64;
  const int srow = lane >> 2;
  const int scol = (lane & 3) * 8;
  const int ch0 = w * 2;
  f32x4 acc[4][4] = {};
  const int nkt = K >> 5;
  const unsigned short* Abase = A + (long)m0 * lda + scol;
  const unsigned short* Bbase = Bt + (long)n0 * ldb + scol;
  for (int kt = 0; kt < nkt; ++kt) {
    __syncthreads();
#pragma unroll
    for (int i = 0; i < 2; ++i) {
      const int ch = ch0 + i;
      load_lds16(Abase + (long)(ch * 16 + srow) * lda + kt * 32, &As[ch * 512]);
      load_lds16(Bbase + (long)(ch * 16 + srow) * ldb + kt * 32, &Bs[ch * 512]);
    }
    __syncthreads();
    bf16x8 fa[4], fb[4];
#pragma unroll
    for (int m = 0; m < 4; ++m)
      fa[m] = *(const bf16x8*)(As + (wm + m * 16 + c) * 32 + g * 8);
#pragma unroll
    for (int n = 0; n < 4; ++n)
      fb[n] = *(const bf16x8*)(Bs + (wn + n * 16 + c) * 32 + g * 8);
#pragma unroll
    for (int m = 0; m < 4; ++m)
#pragma unroll
      for (int n = 0; n < 4; ++n)
        acc[m][n] = __builtin_amdgcn_mfma_f32_16x16x32_bf16(fa[m], fb[n], acc[m][n], 0, 0, 0);
  }
#pragma unroll
  for (int m = 0; m < 4; ++m) {
#pragma unroll
    for (int r = 0; r < 4; ++r) {
      const int row = m0 + wm + m * 16 + 4 * g + r;
#pragma unroll
      for (int n = 0; n < 4; ++n) {
        const int col = n0 + wn + n * 16 + c;
        const long idx = (long)row * ldc + col;
        float v = acc[m][n][r];
        if constexpr (EPI == 0) {
          ((unsigned short*)Cout)[idx] = f2bf(v);
        } else if constexpr (EPI == 1) {
          ((float*)Cout)[idx] = v + ((const float*)aux)[idx];
        } else {
          const float u = bf2f(((const unsigned short*)aux)[idx]);
          const float s = v / (1.0f + __expf(-v));
          ((unsigned short*)Cout)[idx] = f2bf(s * u);
        }
      }
    }
  }
}

// ---------------- k-slice-ring pipelined GEMM -------------------------------
// C[M,N] = A[M,K] @ Bt[N,K]^T, bf16 in, fp32 acc.
// Geometry: WMxWN waves, per-wave FMx FN 16x16 frags; BM=WM*FM*16, BN=WN*FN*16.
// LDS: 4 k-slice slots per operand, slot = [rows][32k] bf16 (conflict-floor
// layout: (4c+g)&7 spreads 64 lanes 8-per-bank-group, distinct addrs).
// Pipeline: phase s computes slice s, stages slice s+3 (3-ahead ~900cyc);
// vmcnt(8/4/0) counted drains + barrier per phase (T3/T4); setprio on MFMA
// cluster (T5). Ring safety: slot (s+3)&3 held slice s-1, fully consumed
// before phase (s-1)'s end barrier; per-wave vmcnt + barrier = cross-thread
// visibility of staged data.
// Grid: 1-D, bid&7 = XCD, each XCD owns a cm x cn rectangle of output tiles
// (L2 locality; requires nbm%cm==0, nbn%cn==0, (nbm/cm)*(nbn/cn)==8).
template <int EPI, int WM, int WN, int FM, int FN>
__global__ __launch_bounds__(WM * WN * 64, 2) void gemm_ks_kernel(
    const unsigned short* __restrict__ A, const unsigned short* __restrict__ Bt,
    void* __restrict__ Cout, const void* __restrict__ aux,
    int M, int N, int K, int lda, int ldb, int ldc, int cm, int cn) {
  constexpr int THREADS = WM * WN * 64;
  constexpr int BM = WM * FM * 16;
  constexpr int BN = WN * FN * 16;
  constexpr int ASLOT = BM * 32;  // elems per k-slice slot
  constexpr int BSLOT = BN * 32;
  constexpr int RPR = THREADS / 4;  // rows staged per load-round
  __shared__ unsigned short As[4 * ASLOT];
  __shared__ unsigned short Bs[4 * BSLOT];

  const int tid = threadIdx.x;
  const int lane = tid & 63, g = lane >> 4, c = lane & 15;
  const int w = tid >> 6, wr = w / WN, wc = w % WN;

  const int nbn = N / BN;
  const int bid = (int)blockIdx.x;
  const int xcd = bid & 7, idx = bid >> 3;
  const int chn = nbn / cn;
  const int crow = xcd / chn, ccol = xcd % chn;
  const int mr = idx / cn, nc2 = idx % cn;
  const int m0 = (crow * cm + mr) * BM;
  const int n0 = (ccol * cn + nc2) * BN;

  const int nks = K >> 5;  // number of 32-wide k-slices
  const int srow = tid >> 2;
  const int kq8 = (tid & 3) * 8;
  const unsigned short* A_ = A + (long)m0 * lda;
  const unsigned short* B_ = Bt + (long)n0 * ldb;

  auto stage = [&](int s) {
    const int slot = s & 3;
    const long kofs = (long)s * 32 + kq8;
#pragma unroll
    for (int j = 0; j < BM / RPR; ++j)
      load_lds16(A_ + (long)(j * RPR + srow) * lda + kofs,
                 &As[slot * ASLOT + (j * THREADS + tid) * 8]);
#pragma unroll
    for (int j = 0; j < BN / RPR; ++j)
      load_lds16(B_ + (long)(j * RPR + srow) * ldb + kofs,
                 &Bs[slot * BSLOT + (j * THREADS + tid) * 8]);
  };

  f32x4 acc[FM][FN] = {};

  stage(0);
  if (nks > 1) stage(1);
  if (nks > 2) stage(2);
  asm volatile("s_waitcnt vmcnt(8)" ::: "memory");
  __builtin_amdgcn_sched_barrier(0);
  __builtin_amdgcn_s_barrier();

  for (int s = 0; s < nks; ++s) {
    const int slot = s & 3;
    const unsigned short* Ap = &As[slot * ASLOT] + (wr * FM * 16 + c) * 32 + g * 8;
    const unsigned short* Bp = &Bs[slot * BSLOT] + (wc * FN * 16 + c) * 32 + g * 8;
    bf16x8 fa[FM], fb[FN];
#pragma unroll
    for (int fm = 0; fm < FM; ++fm) fa[fm] = *(const bf16x8*)(Ap + fm * 512);
#pragma unroll
    for (int fn = 0; fn < FN; ++fn) fb[fn] = *(const bf16x8*)(Bp + fn * 512);
    if (s + 3 < nks) stage(s + 3);
    __builtin_amdgcn_s_setprio(1);
#pragma unroll
    for (int fm = 0; fm < FM; ++fm)
#pragma unroll
      for (int fn = 0; fn < FN; ++fn)
        acc[fm][fn] = __builtin_amdgcn_mfma_f32_16x16x32_bf16(fa[fm], fb[fn], acc[fm][fn], 0, 0, 0);
    __builtin_amdgcn_s_setprio(0);
    if (s + 1 == nks) break;
    if (s <= nks - 4)
      asm volatile("s_waitcnt vmcnt(8)" ::: "memory");
    else if (s == nks - 3)
      asm volatile("s_waitcnt vmcnt(4)" ::: "memory");
    else
      asm volatile("s_waitcnt vmcnt(0)" ::: "memory");
    __builtin_amdgcn_sched_barrier(0);
    __builtin_amdgcn_s_barrier();
  }

#pragma unroll
  for (int fm = 0; fm < FM; ++fm) {
#pragma unroll
    for (int r = 0; r < 4; ++r) {
      const int row = m0 + wr * FM * 16 + fm * 16 + 4 * g + r;
#pragma unroll
      for (int fn = 0; fn < FN; ++fn) {
        const int col = n0 + wc * FN * 16 + fn * 16 + c;
        const long idx2 = (long)row * ldc + col;
        float v = acc[fm][fn][r];
        if constexpr (EPI == 0) {
          ((unsigned short*)Cout)[idx2] = f2bf(v);
        } else if constexpr (EPI == 1) {
          ((float*)Cout)[idx2] = v + ((const float*)aux)[idx2];
        } else {
          const float u = bf2f(((const unsigned short*)aux)[idx2]);
          const float sg = v / (1.0f + __expf(-v));
          ((unsigned short*)Cout)[idx2] = f2bf(sg * u);
        }
      }
    }
  }
}

// ---------------- RoPE tables -----------------------------------------------
__global__ void rope_tables_kernel(float* __restrict__ cost, float* __restrict__ sint) {
  const int idx = blockIdx.x * 256 + threadIdx.x;  // T*64
  const int t = idx >> 6, i = idx & 63;
  const float invf = powf(10000.0f, -(float)i * (1.0f / 64.0f));
  const float ang = (float)t * invf;
  cost[idx] = cosf(ang);
  sint[idx] = sinf(ang);
}

// ---------------- RoPE apply in-place on q,k halves of qkv(bf16) ------------
__global__ __launch_bounds__(256) void rope_apply_kernel(
    unsigned short* __restrict__ qkv, const float* __restrict__ cost,
    const float* __restrict__ sint) {
  const long idx = (long)blockIdx.x * 256 + threadIdx.x;  // BT*16*64*2
  const int i = idx & 63;
  const int h = (idx >> 6) & 15;
  const int qk = (idx >> 10) & 1;
  const int row = idx >> 11;          // 0..BT-1
  const int t = row & (T_SEQ - 1);
  unsigned short* p = qkv + (long)row * (3 * D_MODEL) + qk * D_MODEL + h * D_HEAD + i;
  const float a = bf2f(p[0]);
  const float b = bf2f(p[64]);
  const float cv = cost[t * 64 + i];
  const float sv = sint[t * 64 + i];
  p[0] = f2bf(a * cv - b * sv);
  p[64] = f2bf(b * cv + a * sv);
}

// ---------------- V transpose: qkv v-part -> vt [B,H,128,T] bf16 ------------
__global__ __launch_bounds__(256) void vtrans_kernel(
    const unsigned short* __restrict__ qkv, unsigned short* __restrict__ vt) {
  __shared__ unsigned short tile[32][33];
  const int tx = threadIdx.x, ty = threadIdx.y;
  const int t0 = blockIdx.x * 32, d0 = blockIdx.y * 32;
  const int bh = blockIdx.z;  // b*16+h
  const int b = bh >> 4, h = bh & 15;
#pragma unroll
  for (int i = 0; i < 4; ++i)
    tile[ty + 8 * i][tx] =
        qkv[(long)(b * T_SEQ + t0 + ty + 8 * i) * (3 * D_MODEL) + 2 * D_MODEL + h * D_HEAD + d0 + tx];
  __syncthreads();
#pragma unroll
  for (int i = 0; i < 4; ++i)
    vt[((long)bh * D_HEAD + d0 + ty + 8 * i) * T_SEQ + t0 + tx] = tile[tx][ty + 8 * i];
}

// ---------------- Flash attention (causal), swapped-QK^T --------------------
__global__ __launch_bounds__(256) void attn_kernel(
    const unsigned short* __restrict__ qkv, const unsigned short* __restrict__ vt,
    unsigned short* __restrict__ ctx) {
  __shared__ unsigned short Ks[2][64 * 128];
  __shared__ unsigned short Vs[2][128 * 64];
  const int h = blockIdx.y, b = blockIdx.z;
  const int tid = threadIdx.x;
  const int w = tid >> 6, lane = tid & 63, g = lane >> 4, c = lane & 15;
  const float scale = 0.08838834764831845f;  // 128^-0.5
  const int srcA = (2 * (g & 1)) * 16 + c;
  const int srcB = srcA + 16;
  const bool hi = (g >> 1) != 0;
  const int bh = b * N_HEADS + h;

  const int ssk = (tid & 15) ^ ((tid >> 4) & 7);
  const int ssv = (tid & 7) ^ ((tid >> 3) & 7);
  const unsigned short* Kg = qkv + (long)b * T_SEQ * 3 * D_MODEL + D_MODEL + (long)h * D_HEAD;
  const unsigned short* Vg = vt + (long)bh * D_HEAD * T_SEQ;

  auto stage = [&](int kv0, int bufi) {
#pragma unroll
    for (int i = 0; i < 4; ++i) {
      const int rowk = i * 16 + (tid >> 4);
      load_lds16(Kg + (long)(kv0 + rowk) * (3 * D_MODEL) + ssk * 8,
                 &Ks[bufi][(i * 256 + tid) * 8]);
    }
#pragma unroll
    for (int i = 0; i < 4; ++i) {
      const int rowv = i * 32 + (tid >> 3);
      load_lds16(Vg + (long)rowv * T_SEQ + kv0 + ssv * 8,
                 &Vs[bufi][(i * 256 + tid) * 8]);
    }
  };

  const int cs7 = c & 7;

  for (int pass = 0; pass < 2; ++pass) {
    const int qt = pass ? (NT - 1 - blockIdx.x) : blockIdx.x;
    const int q = qt * 64 + w * 16 + c;

    bf16x8 fq[4];
    const long rowQ = (long)(b * T_SEQ + q) * (3 * D_MODEL) + h * D_HEAD;
#pragma unroll
    for (int ks = 0; ks < 4; ++ks)
      fq[ks] = *(const bf16x8*)(qkv + rowQ + ks * 32 + g * 8);

    f32x4 o[8] = {};
    float mrun = -INFINITY, ell = 0.0f;

    stage(0, 0);
    asm volatile("s_waitcnt vmcnt(0)" ::: "memory");
    __syncthreads();
    int buf = 0;

    for (int kt = 0; kt <= qt; ++kt) {
      const int kv0 = kt * 64;
      if (kt < qt) stage(kv0 + 64, buf ^ 1);

      f32x4 s[4] = {};
#pragma unroll
      for (int fm = 0; fm < 4; ++fm) {
        const unsigned short* kr = &Ks[buf][(fm * 16 + c) * 128];
#pragma unroll
        for (int ks = 0; ks < 4; ++ks) {
          bf16x8 ak = *(const bf16x8*)(kr + ((ks * 4 + g) ^ cs7) * 8);
          s[fm] = __builtin_amdgcn_mfma_f32_16x16x32_bf16(ak, fq[ks], s[fm], 0, 0, 0);
        }
      }
      float pmax = -INFINITY;
      const bool diag = (kt == qt);
#pragma unroll
      for (int fm = 0; fm < 4; ++fm)
#pragma unroll
        for (int r = 0; r < 4; ++r) {
          float sv = s[fm][r] * scale;
          if (diag) {
            const int kp = kv0 + fm * 16 + 4 * g + r;
            if (kp > q) sv = -INFINITY;
          }
          s[fm][r] = sv;
          pmax = fmaxf(pmax, sv);
        }
      pmax = fmaxf(pmax, __shfl_xor(pmax, 16));
      pmax = fmaxf(pmax, __shfl_xor(pmax, 32));
      const float mnew = fmaxf(mrun, pmax);
      const float resc = __expf(mrun - mnew);
      mrun = mnew;
      float rowsum = 0.0f;
#pragma unroll
      for (int fm = 0; fm < 4; ++fm)
#pragma unroll
        for (int r = 0; r < 4; ++r) {
          const float p = __expf(s[fm][r] - mnew);
          s[fm][r] = p;
          rowsum += p;
        }
      rowsum += __shfl_xor(rowsum, 16);
      rowsum += __shfl_xor(rowsum, 32);
      ell = ell * resc + rowsum;
#pragma unroll
      for (int fm = 0; fm < 8; ++fm) o[fm] *= resc;

      bf16x8 pb[2];
#pragma unroll
      for (int k2 = 0; k2 < 2; ++k2) {
        float va[4], vb[4];
#pragma unroll
        for (int r = 0; r < 4; ++r) {
          const float t0 = __shfl(s[k2 * 2][r], srcA);
          const float t1 = __shfl(s[k2 * 2 + 1][r], srcA);
          va[r] = hi ? t1 : t0;
          const float u0 = __shfl(s[k2 * 2][r], srcB);
          const float u1 = __shfl(s[k2 * 2 + 1][r], srcB);
          vb[r] = hi ? u1 : u0;
        }
        bf16x8 pv;
        pv[0] = (__bf16)va[0]; pv[1] = (__bf16)va[1];
        pv[2] = (__bf16)va[2]; pv[3] = (__bf16)va[3];
        pv[4] = (__bf16)vb[0]; pv[5] = (__bf16)vb[1];
        pv[6] = (__bf16)vb[2]; pv[7] = (__bf16)vb[3];
        pb[k2] = pv;
      }
#pragma unroll
      for (int fm = 0; fm < 8; ++fm) {
        const unsigned short* vr = &Vs[buf][(fm * 16 + c) * 64];
#pragma unroll
        for (int k2 = 0; k2 < 2; ++k2) {
          bf16x8 av = *(const bf16x8*)(vr + ((k2 * 4 + g) ^ cs7) * 8);
          o[fm] = __builtin_amdgcn_mfma_f32_16x16x32_bf16(av, pb[k2], o[fm], 0, 0, 0);
        }
      }
      asm volatile("s_waitcnt vmcnt(0)" ::: "memory");
      __syncthreads();
      buf ^= 1;
    }

    const float inv = 1.0f / ell;
    unsigned short* outp = ctx + (long)(b * T_SEQ + q) * D_MODEL + h * D_HEAD;
#pragma unroll
    for (int fm = 0; fm < 8; ++fm) {
      ushort4 pk;
      pk.x = f2bf(o[fm][0] * inv);
      pk.y = f2bf(o[fm][1] * inv);
      pk.z = f2bf(o[fm][2] * inv);
      pk.w = f2bf(o[fm][3] * inv);
      *(ushort4*)(outp + fm * 16 + 4 * g) = pk;
    }
  }
}

// ---------------------------------------------------------------------------
extern "C" void kernel_launch(void* const* d_in, const int* in_sizes, int n_in,
                              void* d_out, int out_size, void* d_ws, size_t ws_size,
                              hipStream_t stream) {
  const float* x = (const float*)d_in[0];
  const float* w_qkv = (const float*)d_in[1];
  const float* w_out = (const float*)d_in[2];
  const float* g1 = (const float*)d_in[3];
  const float* g2 = (const float*)d_in[4];
  const float* w_g = (const float*)d_in[5];
  const float* w_u = (const float*)d_in[6];
  const float* w_o = (const float*)d_in[7];
  float* out = (float*)d_out;

  char* ws = (char*)d_ws;
  size_t off = 0;
  auto take = [&](size_t bytes) {
    char* p = ws + off;
    off += (bytes + 255) & ~(size_t)255;
    return p;
  };

  // weight region (phase A and phase B alias the same memory)
  char* Wreg = take((size_t)3 * D_FF * D_MODEL * 2);  // 100.66 MB
  unsigned short* wTqkv = (unsigned short*)Wreg;
  unsigned short* wTout = (unsigned short*)(Wreg + (size_t)3 * D_MODEL * D_MODEL * 2);
  unsigned short* wTg = (unsigned short*)Wreg;
  unsigned short* wTu = (unsigned short*)(Wreg + (size_t)D_FF * D_MODEL * 2);
  unsigned short* wTo = (unsigned short*)(Wreg + (size_t)2 * D_FF * D_MODEL * 2);

  // activation region (phase A and phase B alias the same memory)
  const size_t qkv_b = (size_t)BT * 3 * D_MODEL * 2;
  const size_t vt_b = (size_t)B_SZ * N_HEADS * D_HEAD * T_SEQ * 2;
  const size_t ctx_b = (size_t)BT * D_MODEL * 2;
  char* AR = take(qkv_b + vt_b + ctx_b);  // 83.9 MB
  unsigned short* qkvb = (unsigned short*)AR;
  unsigned short* vtb = (unsigned short*)(AR + qkv_b);
  unsigned short* ctxb = (unsigned short*)(AR + qkv_b + vt_b);
  unsigned short* gbuf = (unsigned short*)AR;                                  // 33.6 MB
  unsigned short* ubuf = (unsigned short*)(AR + (size_t)BT * (D_FF / 2) * 2);  // 33.6 MB

  float* x1 = (float*)take((size_t)BT * D_MODEL * 4);
  unsigned short* hb = (unsigned short*)take((size_t)BT * D_MODEL * 2);
  float* cost = (float*)take((size_t)T_SEQ * 64 * 4);
  float* sint = (float*)take((size_t)T_SEQ * 64 * 4);

  const dim3 tb(32, 8);

  // ---- phase A: attention ----
  transpose_cast_kernel<<<dim3(3 * D_MODEL / 32, D_MODEL / 32), tb, 0, stream>>>(w_qkv, wTqkv, D_MODEL, 3 * D_MODEL);
  transpose_cast_kernel<<<dim3(D_MODEL / 32, D_MODEL / 32), tb, 0, stream>>>(w_out, wTout, D_MODEL, D_MODEL);
  rope_tables_kernel<<<T_SEQ * 64 / 256, 256, 0, stream>>>(cost, sint);

  rmsnorm_cast_kernel<<<BT, 256, 0, stream>>>(x, g1, hb);
  // QKV: 256^2 k-slice kernel; nbm=16, nbn=24 -> 384 blocks, XCD chunk 8x6
  gemm_ks_kernel<0, 2, 4, 8, 4><<<384, 512, 0, stream>>>(
      hb, wTqkv, qkvb, nullptr, BT, 3 * D_MODEL, D_MODEL, D_MODEL, D_MODEL, 3 * D_MODEL, 8, 6);
  rope_apply_kernel<<<(BT * N_HEADS * 64 * 2) / 256, 256, 0, stream>>>(qkvb, cost, sint);
  vtrans_kernel<<<dim3(T_SEQ / 32, D_HEAD / 32, B_SZ * N_HEADS), tb, 0, stream>>>(qkvb, vtb);
  attn_kernel<<<dim3(NT / 2, N_HEADS, B_SZ), 256, 0, stream>>>(qkvb, vtb, ctxb);
  // out-proj: 128^2 k-slice kernel; nbm=32, nbn=16 -> 512 blocks, chunk 8x8
  gemm_ks_kernel<1, 2, 2, 4, 4><<<512, 256, 0, stream>>>(
      ctxb, wTout, x1, x, BT, D_MODEL, D_MODEL, D_MODEL, D_MODEL, D_MODEL, 8, 8);

  // ---- phase B: MLP, N-halved (M=4096 everywhere) ----
  transpose_cast_kernel<<<dim3(D_FF / 32, D_MODEL / 32), tb, 0, stream>>>(w_g, wTg, D_MODEL, D_FF);
  transpose_cast_kernel<<<dim3(D_FF / 32, D_MODEL / 32), tb, 0, stream>>>(w_u, wTu, D_MODEL, D_FF);
  transpose_cast_kernel<<<dim3(D_MODEL / 32, D_FF / 32), tb, 0, stream>>>(w_o, wTo, D_FF, D_MODEL);
  rmsnorm_cast_kernel<<<BT, 256, 0, stream>>>(x1, g2, hb);

  const int NH = D_FF / 2;  // 4096 ff-columns per half
  for (int half = 0; half < 2; ++half) {
    const unsigned short* wTu_h = wTu + (size_t)half * NH * D_MODEL;
    const unsigned short* wTg_h = wTg + (size_t)half * NH * D_MODEL;
    const unsigned short* wTo_h = wTo + (size_t)half * NH;  // K-slice of [2048][8192]
    // up half: 256^2 k-slice; nbm=16, nbn=16 -> 256 blocks, chunk 4x8
    gemm_ks_kernel<0, 2, 4, 8, 4><<<256, 512, 0, stream>>>(
        hb, wTu_h, ubuf, nullptr, BT, NH, D_MODEL, D_MODEL, D_MODEL, NH, 4, 8);
    // gate half + fused SwiGLU (reads ubuf)
    gemm_ks_kernel<2, 2, 4, 8, 4><<<256, 512, 0, stream>>>(
        hb, wTg_h, gbuf, ubuf, BT, NH, D_MODEL, D_MODEL, D_MODEL, NH, 4, 8);
    // down half: 128^2 k-slice; nbm=32, nbn=16 -> 512 blocks, chunk 8x8
    gemm_ks_kernel<1, 2, 2, 4, 4><<<512, 256, 0, stream>>>(
        gbuf, wTo_h, out, (half == 0) ? x1 : out, BT, D_MODEL, NH, NH, D_FF, D_MODEL, 8, 8);
  }
}